// Round 1
// baseline (1293.423 us; speedup 1.0000x reference)
//
#include <hip/hip_runtime.h>
#include <cstdint>

// Problem constants (setup_inputs is fixed: nx=2048, nz=256, B=512, S=10, k=25, T=30)
#define NX 2048
#define NZ 256
#define NB 512
#define NS 10
#define NK 25
#define NT 30
#define SBTOT (NS * NB)  // 5120

// d_out flat layout (all float32): q, samples_z, ps, xouts, loss
#define OFF_Q 0
#define OFF_SAMP (NB * NZ)                 // 131072
#define OFF_PS (OFF_SAMP + SBTOT * NZ)     // 1441792
#define OFF_XO (OFF_PS + SBTOT * NX)       // 11927552
#define OFF_LOSS (OFF_XO + SBTOT * NX)     // 22413312

// ---------------- JAX Threefry-2x32 (exact) ----------------
__host__ __device__ inline void tf2x32(uint32_t k0, uint32_t k1, uint32_t x0, uint32_t x1,
                                       uint32_t& o0, uint32_t& o1) {
  uint32_t k2 = k0 ^ k1 ^ 0x1BD11BDAu;
  x0 += k0; x1 += k1;
#define TF_R(r) { x0 += x1; x1 = (x1 << (r)) | (x1 >> (32 - (r))); x1 ^= x0; }
  TF_R(13) TF_R(15) TF_R(26) TF_R(6)
  x0 += k1; x1 += k2 + 1u;
  TF_R(17) TF_R(29) TF_R(16) TF_R(24)
  x0 += k2; x1 += k0 + 2u;
  TF_R(13) TF_R(15) TF_R(26) TF_R(6)
  x0 += k0; x1 += k1 + 3u;
  TF_R(17) TF_R(29) TF_R(16) TF_R(24)
  x0 += k1; x1 += k2 + 4u;
  TF_R(13) TF_R(15) TF_R(26) TF_R(6)
  x0 += k2; x1 += k0 + 5u;
#undef TF_R
  o0 = x0; o1 = x1;
}

// JAX threefry_2x32 over iota(n): flat element i (n even, h=n/2):
//   i <  h : o0 of tf(key, i, i+h)
//   i >= h : o1 of tf(key, i-h, i)
__device__ inline uint32_t tf_select(uint32_t k0, uint32_t k1, uint32_t i, uint32_t h) {
  bool lo = i < h;
  uint32_t x0 = lo ? i : i - h;
  uint32_t x1 = lo ? i + h : i;
  uint32_t o0, o1;
  tf2x32(k0, k1, x0, x1, o0, o1);
  return lo ? o0 : o1;
}

__device__ inline float tf_uniform(uint32_t k0, uint32_t k1, uint32_t i, uint32_t h) {
  uint32_t r = tf_select(k0, k1, i, h);
  return __uint_as_float(0x3f800000u | (r >> 9)) - 1.0f;  // [0,1), exactly JAX
}

__device__ inline float sigclip(float a) {
  float p = 1.0f / (1.0f + __expf(-a));
  return fminf(fmaxf(p, 1e-6f), 1.0f - 1e-6f);
}

__device__ inline float blockReduceSum256(float v, volatile float* s4) {
#pragma unroll
  for (int o = 32; o > 0; o >>= 1) v += __shfl_down(v, o);
  __syncthreads();
  if ((threadIdx.x & 63) == 0) s4[threadIdx.x >> 6] = v;
  __syncthreads();
  return s4[0] + s4[1] + s4[2] + s4[3];
}

// ---------------- K0: pz terms from z_bias ----------------
__global__ __launch_bounds__(256) void k0_pz(const float* __restrict__ z_bias,
                                             float* __restrict__ d_lpz,
                                             float* __restrict__ basepz) {
  __shared__ float red[4];
  int z = threadIdx.x;
  float pz = sigclip(z_bias[z]);
  float lp = __logf(pz), l1 = __logf(1.0f - pz);
  d_lpz[z] = lp - l1;
  float s = blockReduceSum256(l1, red);
  if (z == 0) *basepz = s;
}

// ---------------- K1: q = clip(sigmoid(xin @ U^T + z_bias)) + log terms ----------------
#define K1_ROWS 4
__global__ __launch_bounds__(256) void k1_q(const float* __restrict__ xin,
                                            const float* __restrict__ U,
                                            const float* __restrict__ z_bias,
                                            float* __restrict__ outq,
                                            float* __restrict__ d_lq,
                                            float* __restrict__ baseq) {
  __shared__ float xs[K1_ROWS][NX];
  __shared__ float red[4];
  int b0 = blockIdx.x * K1_ROWS;
  int tid = threadIdx.x;
  const float4* src = (const float4*)(xin + (size_t)b0 * NX);
  float4* dst = (float4*)(&xs[0][0]);
  for (int i = tid; i < K1_ROWS * NX / 4; i += 256) dst[i] = src[i];
  __syncthreads();
  int z = tid;
  float acc[K1_ROWS];
#pragma unroll
  for (int r = 0; r < K1_ROWS; ++r) acc[r] = 0.0f;
  const float4* U4 = (const float4*)(U + (size_t)z * NX);
  for (int i4 = 0; i4 < NX / 4; ++i4) {
    float4 u = U4[i4];
    int i = i4 * 4;
#pragma unroll
    for (int r = 0; r < K1_ROWS; ++r)
      acc[r] += u.x * xs[r][i] + u.y * xs[r][i + 1] + u.z * xs[r][i + 2] + u.w * xs[r][i + 3];
  }
  float zb = z_bias[z];
  for (int r = 0; r < K1_ROWS; ++r) {
    int b = b0 + r;
    float q = sigclip(acc[r] + zb);
    outq[b * NZ + z] = q;
    float lq = __logf(q), l1 = __logf(1.0f - q);
    d_lq[b * NZ + z] = lq - l1;
    float s = blockReduceSum256(l1, red);
    if (tid == 0) baseq[b] = s;
  }
}

// ---------------- K2: samples_z + packed bits + tails ----------------
__global__ __launch_bounds__(256) void k2_samples(const float* __restrict__ q,
                                                  const float* __restrict__ d_lq,
                                                  const float* __restrict__ d_lpz,
                                                  float* __restrict__ samp_out,
                                                  unsigned long long* __restrict__ Spack,
                                                  float* __restrict__ qtail,
                                                  float* __restrict__ ptail,
                                                  uint32_t kz0, uint32_t kz1) {
  __shared__ float red[4];
  int sb = blockIdx.x;        // 0..5119, (s,b) = (sb/512, sb%512)
  int z = threadIdx.x;
  int b = sb & (NB - 1);
  uint32_t i = (uint32_t)sb * NZ + z;
  const uint32_t h = (uint32_t)SBTOT * NZ / 2;
  float u = tf_uniform(kz0, kz1, i, h);
  float qv = q[b * NZ + z];
  int smp = (u < qv) ? 1 : 0;
  samp_out[i] = (float)smp;
  unsigned long long m = __ballot(smp);
  if ((z & 63) == 0) Spack[sb * 4 + (z >> 6)] = m;
  float dq = (z >= NK && smp) ? d_lq[b * NZ + z] : 0.0f;
  float dp = (z >= NK && smp) ? d_lpz[z] : 0.0f;
  float sq = blockReduceSum256(dq, red);
  float sp = blockReduceSum256(dp, red);
  if (z == 0) { qtail[sb] = sq; ptail[sb] = sp; }
}

// ---------------- K3: base = samples @ V^T + x_bias; ps; xouts ----------------
__global__ __launch_bounds__(256) void k3_gemm(const float* __restrict__ samples,
                                               const float* __restrict__ V,
                                               const float* __restrict__ x_bias,
                                               float* __restrict__ base,
                                               float* __restrict__ ps_out,
                                               float* __restrict__ xo_out,
                                               uint32_t kx0, uint32_t kx1) {
  __shared__ float As[64][17];  // +1 pad: avoid 16-way bank conflict on Bs-style reads
  __shared__ float Bs[64][17];
  int tid = threadIdx.x;
  int tx = tid & 15, ty = tid >> 4;
  int x0 = blockIdx.x * 64;
  int sb0 = blockIdx.y * 64;
  int lr = tid >> 2;
  int lk = (tid & 3) << 2;
  float acc[4][4];
#pragma unroll
  for (int i = 0; i < 4; ++i)
#pragma unroll
    for (int j = 0; j < 4; ++j) acc[i][j] = 0.0f;

  for (int k0 = 0; k0 < NZ; k0 += 16) {
    float4 a4 = *(const float4*)(samples + (size_t)(sb0 + lr) * NZ + k0 + lk);
    float4 b4 = *(const float4*)(V + (size_t)(x0 + lr) * NZ + k0 + lk);
    As[lr][lk] = a4.x; As[lr][lk + 1] = a4.y; As[lr][lk + 2] = a4.z; As[lr][lk + 3] = a4.w;
    Bs[lr][lk] = b4.x; Bs[lr][lk + 1] = b4.y; Bs[lr][lk + 2] = b4.z; Bs[lr][lk + 3] = b4.w;
    __syncthreads();
#pragma unroll
    for (int kk = 0; kk < 16; ++kk) {
      float a_[4], b_[4];
#pragma unroll
      for (int i = 0; i < 4; ++i) a_[i] = As[ty * 4 + i][kk];
#pragma unroll
      for (int j = 0; j < 4; ++j) b_[j] = Bs[tx * 4 + j][kk];
#pragma unroll
      for (int i = 0; i < 4; ++i)
#pragma unroll
        for (int j = 0; j < 4; ++j) acc[i][j] += a_[i] * b_[j];
    }
    __syncthreads();
  }
  const uint32_t h = (uint32_t)SBTOT * NX / 2;
  float xb[4];
#pragma unroll
  for (int j = 0; j < 4; ++j) xb[j] = x_bias[x0 + tx * 4 + j];
#pragma unroll
  for (int i = 0; i < 4; ++i) {
    int sb = sb0 + ty * 4 + i;
    float bs[4], pv[4], xv[4];
#pragma unroll
    for (int j = 0; j < 4; ++j) {
      int x = x0 + tx * 4 + j;
      float a = acc[i][j] + xb[j];
      bs[j] = a;
      float p = sigclip(a);
      pv[j] = p;
      uint32_t fi = (uint32_t)sb * NX + x;
      float u = tf_uniform(kx0, kx1, fi, h);
      xv[j] = (u < p) ? 1.0f : 0.0f;
    }
    int off = sb * NX + x0 + tx * 4;
    *(float4*)(base + off) = make_float4(bs[0], bs[1], bs[2], bs[3]);
    *(float4*)(ps_out + off) = make_float4(pv[0], pv[1], pv[2], pv[3]);
    *(float4*)(xo_out + off) = make_float4(xv[0], xv[1], xv[2], xv[3]);
  }
}

// ---------------- K4: GF(2) row reduce per t (exact replica incl. no-pivot swap to k-1) ----------------
__global__ __launch_bounds__(64) void k4_rowreduce(unsigned long long* __restrict__ Ct,
                                                   uint32_t* __restrict__ bpmask,
                                                   uint32_t kA0, uint32_t kA1,
                                                   uint32_t kb0, uint32_t kb1) {
  int t = blockIdx.x;
  int lane = threadIdx.x;  // one wave; lanes 0..24 own rows
  unsigned long long w0 = 0, w1 = 0, w2 = 0, w3 = 0;
  unsigned int bbit = 0;
  if (lane < NK) {
    const uint32_t hA = (uint32_t)NT * NK * NZ / 2;  // 96000
    uint32_t rowbase = (uint32_t)(t * NK + lane) * NZ;
    for (int z = 0; z < NZ; ++z) {
      uint32_t r = tf_select(kA0, kA1, rowbase + z, hA);
      unsigned long long bit = (r >> 31) ? 0ull : 1ull;  // u<0.5 <=> top bit 0
      if (z < 64) w0 |= bit << z;
      else if (z < 128) w1 |= bit << (z - 64);
      else if (z < 192) w2 |= bit << (z - 128);
      else w3 |= bit << (z - 192);
    }
    const uint32_t hb = (uint32_t)NT * NK / 2;  // 375
    uint32_t rb = tf_select(kb0, kb1, (uint32_t)(t * NK + lane), hb);
    bbit = (rb >> 31) ? 0u : 1u;
  }
  for (int i = 0; i < NK; ++i) {
    int mybit = (int)((w0 >> i) & 1ull);  // i<25 -> word0
    unsigned long long mask = __ballot(lane < NK && mybit);
    unsigned long long cand = mask & (~0ull << i);
    int p = cand ? __builtin_ctzll(cand) : (NK - 1);
    int srcl = (lane == i) ? p : ((lane == p) ? i : lane);
    w0 = __shfl(w0, srcl); w1 = __shfl(w1, srcl); w2 = __shfl(w2, srcl); w3 = __shfl(w3, srcl);
    bbit = __shfl(bbit, srcl);
    unsigned long long p0 = __shfl(w0, i), p1 = __shfl(w1, i), p2 = __shfl(w2, i), p3 = __shfl(w3, i);
    unsigned int pvb = __shfl(bbit, i);
    int nb2 = (int)((w0 >> i) & 1ull);
    if (lane < NK && lane != i && nb2) {
      w0 ^= p0; w1 ^= p1; w2 ^= p2; w3 ^= p3; bbit ^= pvb;
    }
  }
  if (lane < NK) {
    w0 &= ~((1ull << NK) - 1ull);  // only columns z>=k feed proj
    unsigned long long* dstp = Ct + (size_t)(t * NK + lane) * 4;
    dstp[0] = w0; dstp[1] = w1; dstp[2] = w2; dstp[3] = w3;
  }
  unsigned long long bm = __ballot(lane < NK && bbit);
  if (lane == 0) bpmask[t] = (uint32_t)bm & 0x1FFFFFFu;
}

// ---------------- K5: proj bits per (t,s,b) ----------------
__global__ __launch_bounds__(256) void k5_proj(const unsigned long long* __restrict__ Spack,
                                               const unsigned long long* __restrict__ Ct,
                                               const uint32_t* __restrict__ bpmask,
                                               uint32_t* __restrict__ projbits) {
  int e = blockIdx.x * 256 + threadIdx.x;  // < NT*SBTOT = 153600
  int t = e / SBTOT, sb = e - t * SBTOT;
  unsigned long long s0 = Spack[sb * 4 + 0], s1 = Spack[sb * 4 + 1];
  unsigned long long s2 = Spack[sb * 4 + 2], s3 = Spack[sb * 4 + 3];
  uint32_t bp = bpmask[t];
  uint32_t pb = 0;
#pragma unroll
  for (int j = 0; j < NK; ++j) {
    const unsigned long long* C = Ct + (size_t)(t * NK + j) * 4;
    int par = __popcll(s0 & C[0]) + __popcll(s1 & C[1]) + __popcll(s2 & C[2]) + __popcll(s3 & C[3]);
    uint32_t bit = ((uint32_t)par ^ (bp >> j)) & 1u;
    pb |= bit << j;
  }
  projbits[e] = pb;
}

// ---------------- K6: logp_x[t,s,b] via base + (proj - s25)@Vk^T, softplus ----------------
#define TCH 10
__global__ __launch_bounds__(256) void k6_logpx(const float* __restrict__ base,
                                                const float* __restrict__ V,
                                                const float* __restrict__ xin,
                                                const uint32_t* __restrict__ projbits,
                                                const unsigned long long* __restrict__ Spack,
                                                float* __restrict__ logpx) {
  __shared__ float red[4];
  int sb = blockIdx.x;
  int t0 = blockIdx.y * TCH;
  int b = sb & (NB - 1);
  int tid = threadIdx.x;
  uint32_t s25 = (uint32_t)(Spack[sb * 4] & 0x1FFFFFFull);  // block-uniform -> SGPR
  uint32_t pb[TCH];
#pragma unroll
  for (int tc = 0; tc < TCH; ++tc) pb[tc] = projbits[(t0 + tc) * SBTOT + sb];
  const float* brow = base + (size_t)sb * NX;
  const float* xrow = xin + (size_t)b * NX;
  float acc[TCH];
#pragma unroll
  for (int tc = 0; tc < TCH; ++tc) acc[tc] = 0.0f;
#pragma unroll 1
  for (int xi = 0; xi < NX / 256; ++xi) {
    int x = xi * 256 + tid;
    float bv = brow[x];
    bool x1 = xrow[x] > 0.5f;
    float v[28];
    const float4* vr = (const float4*)(V + (size_t)x * NZ);
#pragma unroll
    for (int qd = 0; qd < 7; ++qd) {
      float4 f = vr[qd];
      v[qd * 4] = f.x; v[qd * 4 + 1] = f.y; v[qd * 4 + 2] = f.z; v[qd * 4 + 3] = f.w;
    }
    float vs = 0.0f;
#pragma unroll
    for (int j = 0; j < NK; ++j) vs += ((s25 >> j) & 1u) ? v[j] : 0.0f;
    float bvs = bv - vs;
#pragma unroll
    for (int tc = 0; tc < TCH; ++tc) {
      float vp = 0.0f;
      uint32_t m = pb[tc];
#pragma unroll
      for (int j = 0; j < NK; ++j) vp += ((m >> j) & 1u) ? v[j] : 0.0f;
      float a = bvs + vp;
      // clamp reproduces clip(sigmoid, eps, 1-eps) then log, to <1e-9
      a = fminf(fmaxf(a, -13.8155095f), 13.8155095f);
      float y = x1 ? -a : a;
      float l = fmaxf(y, 0.0f) + __logf(1.0f + __expf(-fabsf(y)));  // softplus(y)
      acc[tc] -= l;  // log p(x-bit) = -softplus
    }
  }
#pragma unroll 1
  for (int tc = 0; tc < TCH; ++tc) {
    float s = blockReduceSum256(acc[tc], red);
    if (tid == 0) logpx[(size_t)(t0 + tc) * SBTOT + sb] = s;
  }
}

// ---------------- K7: per-t weighted reduction over (s,b) ----------------
__global__ __launch_bounds__(512) void k7_reduce(const float* __restrict__ logpx,
                                                 const uint32_t* __restrict__ projbits,
                                                 const float* __restrict__ qtail,
                                                 const float* __restrict__ ptail,
                                                 const float* __restrict__ baseq,
                                                 const float* __restrict__ d_lq,
                                                 const float* __restrict__ d_lpz,
                                                 const float* __restrict__ basepz,
                                                 double* __restrict__ pelbo) {
  __shared__ double red8[8];
  int t = blockIdx.x;
  int b = threadIdx.x;
  float dlq[NK];
#pragma unroll
  for (int j = 0; j < NK; ++j) dlq[j] = d_lq[b * NZ + j];
  float bq = baseq[b];
  float bpz = *basepz;
  float lq[NS], lp[NS];
#pragma unroll
  for (int s = 0; s < NS; ++s) {
    int sb = s * NB + b;
    uint32_t m = projbits[t * SBTOT + sb];
    float sq = 0.0f, sp = 0.0f;
#pragma unroll
    for (int j = 0; j < NK; ++j) {
      float on = (float)((m >> j) & 1u);
      sq += on * dlq[j];
      sp += on * d_lpz[j];
    }
    lq[s] = bq + qtail[sb] + sq;
    lp[s] = logpx[t * SBTOT + sb] + bpz + ptail[sb] + sp;
  }
  float mx = lq[0];
#pragma unroll
  for (int s = 1; s < NS; ++s) mx = fmaxf(mx, lq[s]);
  float den = 0.0f, num = 0.0f;
#pragma unroll
  for (int s = 0; s < NS; ++s) {
    float w = __expf(lq[s] - mx);
    den += w;
    num += w * (lq[s] - lp[s]);  // wavg(logq - logp); loss = mean_t sum_b of this
  }
  double v = (double)(num / den);
#pragma unroll
  for (int o = 32; o > 0; o >>= 1) v += __shfl_down(v, o);
  __syncthreads();
  if ((b & 63) == 0) red8[b >> 6] = v;
  __syncthreads();
  if (b == 0) {
    double s = 0.0;
    for (int i = 0; i < 8; ++i) s += red8[i];
    pelbo[t] = s;
  }
}

// ---------------- K8: final loss ----------------
__global__ __launch_bounds__(64) void k8_loss(const double* __restrict__ pelbo,
                                              float* __restrict__ out_loss) {
  int t = threadIdx.x;
  double v = (t < NT) ? pelbo[t] : 0.0;
#pragma unroll
  for (int o = 32; o > 0; o >>= 1) v += __shfl_down(v, o);
  if (t == 0) *out_loss = (float)(v / (double)NT);
}

extern "C" void kernel_launch(void* const* d_in, const int* in_sizes, int n_in,
                              void* d_out, int out_size, void* d_ws, size_t ws_size,
                              hipStream_t stream) {
  const float* xin = (const float*)d_in[0];
  const float* U = (const float*)d_in[1];
  const float* V = (const float*)d_in[2];
  const float* x_bias = (const float*)d_in[3];
  const float* z_bias = (const float*)d_in[4];
  // d_in[5..7] = S,k,T (fixed 10,25,30 per setup_inputs) -- hardcoded
  float* out = (float*)d_out;

  // workspace layout (all offsets 16B-aligned; total ~43.9 MB)
  char* p = (char*)d_ws;
  float* base = (float*)p;                 p += (size_t)SBTOT * NX * 4;   // 41,943,040
  float* d_lq = (float*)p;                 p += (size_t)NB * NZ * 4;      // 524,288
  float* baseq = (float*)p;                p += (size_t)NB * 4;
  float* d_lpz = (float*)p;                p += (size_t)NZ * 4;
  float* basepz = (float*)p;               p += 16;
  unsigned long long* Spack = (unsigned long long*)p; p += (size_t)SBTOT * 4 * 8;
  float* qtail = (float*)p;                p += (size_t)SBTOT * 4;
  float* ptail = (float*)p;                p += (size_t)SBTOT * 4;
  unsigned long long* Ct = (unsigned long long*)p;    p += (size_t)NT * NK * 4 * 8;
  uint32_t* bpm = (uint32_t*)p;            p += 128;
  uint32_t* projb = (uint32_t*)p;          p += (size_t)NT * SBTOT * 4;
  float* logpx = (float*)p;                p += (size_t)NT * SBTOT * 4;
  double* pelbo = (double*)p;              p += (size_t)NT * 8;
  (void)ws_size; (void)in_sizes; (void)n_in; (void)out_size;

  // JAX: key(42) -> split 4 -> kz,kx,kA,kb. counts=iota(8), halves [0..3]/[4..7]
  uint32_t o0[4], o1[4];
  for (int j = 0; j < 4; ++j) tf2x32(0u, 42u, (uint32_t)j, (uint32_t)(4 + j), o0[j], o1[j]);
  uint32_t kz0 = o0[0], kz1 = o0[1];
  uint32_t kx0 = o0[2], kx1 = o0[3];
  uint32_t kA0 = o1[0], kA1 = o1[1];
  uint32_t kb0 = o1[2], kb1 = o1[3];

  k0_pz<<<1, 256, 0, stream>>>(z_bias, d_lpz, basepz);
  k1_q<<<NB / K1_ROWS, 256, 0, stream>>>(xin, U, z_bias, out + OFF_Q, d_lq, baseq);
  k2_samples<<<SBTOT, 256, 0, stream>>>(out + OFF_Q, d_lq, d_lpz, out + OFF_SAMP,
                                        Spack, qtail, ptail, kz0, kz1);
  dim3 g3(NX / 64, SBTOT / 64);
  k3_gemm<<<g3, 256, 0, stream>>>(out + OFF_SAMP, V, x_bias, base,
                                  out + OFF_PS, out + OFF_XO, kx0, kx1);
  k4_rowreduce<<<NT, 64, 0, stream>>>(Ct, bpm, kA0, kA1, kb0, kb1);
  k5_proj<<<NT * SBTOT / 256, 256, 0, stream>>>(Spack, Ct, bpm, projb);
  dim3 g6(SBTOT, NT / TCH);
  k6_logpx<<<g6, 256, 0, stream>>>(base, V, xin, projb, Spack, logpx);
  k7_reduce<<<NT, 512, 0, stream>>>(logpx, projb, qtail, ptail, baseq, d_lq,
                                    d_lpz, basepz, pelbo);
  k8_loss<<<1, 64, 0, stream>>>(pelbo, out + OFF_LOSS);
}

// Round 2
// 523.376 us; speedup vs baseline: 2.4713x; 2.4713x over previous
//
#include <hip/hip_runtime.h>
#include <cstdint>

// Problem constants (setup_inputs fixed: nx=2048, nz=256, B=512, S=10, k=25, T=30)
#define NX 2048
#define NZ 256
#define NB 512
#define NS 10
#define NK 25
#define NT 30
#define SBTOT (NS * NB)  // 5120

// d_out flat layout (all float32): q, samples_z, ps, xouts, loss
#define OFF_Q 0
#define OFF_SAMP (NB * NZ)
#define OFF_PS (OFF_SAMP + SBTOT * NZ)
#define OFF_XO (OFF_PS + SBTOT * NX)
#define OFF_LOSS (OFF_XO + SBTOT * NX)

typedef unsigned long long ull;
typedef __bf16 bf16x8 __attribute__((ext_vector_type(8)));
typedef float f32x4 __attribute__((ext_vector_type(4)));

// ---------------- JAX Threefry-2x32 (exact) ----------------
__host__ __device__ inline void tf2x32(uint32_t k0, uint32_t k1, uint32_t x0, uint32_t x1,
                                       uint32_t& o0, uint32_t& o1) {
  uint32_t k2 = k0 ^ k1 ^ 0x1BD11BDAu;
  x0 += k0; x1 += k1;
#define TF_R(r) { x0 += x1; x1 = (x1 << (r)) | (x1 >> (32 - (r))); x1 ^= x0; }
  TF_R(13) TF_R(15) TF_R(26) TF_R(6)
  x0 += k1; x1 += k2 + 1u;
  TF_R(17) TF_R(29) TF_R(16) TF_R(24)
  x0 += k2; x1 += k0 + 2u;
  TF_R(13) TF_R(15) TF_R(26) TF_R(6)
  x0 += k0; x1 += k1 + 3u;
  TF_R(17) TF_R(29) TF_R(16) TF_R(24)
  x0 += k1; x1 += k2 + 4u;
  TF_R(13) TF_R(15) TF_R(26) TF_R(6)
  x0 += k2; x1 += k0 + 5u;
#undef TF_R
  o0 = x0; o1 = x1;
}

// JAX threefry over iota(n): element i (h=n/2): i<h -> o0(i,i+h); else o1(i-h,i)
__device__ inline uint32_t tf_select(uint32_t k0, uint32_t k1, uint32_t i, uint32_t h) {
  bool lo = i < h;
  uint32_t x0 = lo ? i : i - h;
  uint32_t x1 = lo ? i + h : i;
  uint32_t o0, o1;
  tf2x32(k0, k1, x0, x1, o0, o1);
  return lo ? o0 : o1;
}

__device__ inline float tf_uniform(uint32_t k0, uint32_t k1, uint32_t i, uint32_t h) {
  uint32_t r = tf_select(k0, k1, i, h);
  return __uint_as_float(0x3f800000u | (r >> 9)) - 1.0f;  // [0,1), exactly JAX
}

__device__ inline float sigclip(float a) {
  float p = 1.0f / (1.0f + __expf(-a));
  return fminf(fmaxf(p, 1e-6f), 1.0f - 1e-6f);
}

__device__ inline float blockReduceSum256(float v, volatile float* s4) {
#pragma unroll
  for (int o = 32; o > 0; o >>= 1) v += __shfl_down(v, o);
  __syncthreads();
  if ((threadIdx.x & 63) == 0) s4[threadIdx.x >> 6] = v;
  __syncthreads();
  return s4[0] + s4[1] + s4[2] + s4[3];
}

// softplus(sign-applied clamp) — log p(x-bit) = -sp
__device__ inline float sp_eval(float a, uint32_t sm) {
  a = fminf(fmaxf(a, -13.8155095f), 13.8155095f);
  float y = __int_as_float(__float_as_int(a) ^ sm);
  return fmaxf(y, 0.0f) + __logf(1.0f + __expf(-fabsf(y)));
}

// ---------------- K0: pz terms ----------------
__global__ __launch_bounds__(256) void k0_pz(const float* __restrict__ z_bias,
                                             float* __restrict__ d_lpz,
                                             float* __restrict__ basepz) {
  __shared__ float red[4];
  int z = threadIdx.x;
  float pz = sigclip(z_bias[z]);
  float lp = __logf(pz), l1 = __logf(1.0f - pz);
  d_lpz[z] = lp - l1;
  float s = blockReduceSum256(l1, red);
  if (z == 0) *basepz = s;
}

// ---------------- K1: q = clip(sigmoid(xin @ U^T + z_bias)) ----------------
#define K1_ROWS 4
__global__ __launch_bounds__(256) void k1_q(const float* __restrict__ xin,
                                            const float* __restrict__ U,
                                            const float* __restrict__ z_bias,
                                            float* __restrict__ outq,
                                            float* __restrict__ d_lq,
                                            float* __restrict__ baseq) {
  __shared__ float xs[K1_ROWS][NX];
  __shared__ float red[4];
  int b0 = blockIdx.x * K1_ROWS;
  int tid = threadIdx.x;
  const float4* src = (const float4*)(xin + (size_t)b0 * NX);
  float4* dst = (float4*)(&xs[0][0]);
  for (int i = tid; i < K1_ROWS * NX / 4; i += 256) dst[i] = src[i];
  __syncthreads();
  int z = tid;
  float acc[K1_ROWS];
#pragma unroll
  for (int r = 0; r < K1_ROWS; ++r) acc[r] = 0.0f;
  const float4* U4 = (const float4*)(U + (size_t)z * NX);
  for (int i4 = 0; i4 < NX / 4; ++i4) {
    float4 u = U4[i4];
    int i = i4 * 4;
#pragma unroll
    for (int r = 0; r < K1_ROWS; ++r)
      acc[r] += u.x * xs[r][i] + u.y * xs[r][i + 1] + u.z * xs[r][i + 2] + u.w * xs[r][i + 3];
  }
  float zb = z_bias[z];
  for (int r = 0; r < K1_ROWS; ++r) {
    int b = b0 + r;
    float q = sigclip(acc[r] + zb);
    outq[b * NZ + z] = q;
    float lq = __logf(q), l1 = __logf(1.0f - q);
    d_lq[b * NZ + z] = lq - l1;
    float s = blockReduceSum256(l1, red);
    if (tid == 0) baseq[b] = s;
  }
}

// ---------------- K2: samples_z + packed bits + tails ----------------
__global__ __launch_bounds__(256) void k2_samples(const float* __restrict__ q,
                                                  const float* __restrict__ d_lq,
                                                  const float* __restrict__ d_lpz,
                                                  float* __restrict__ samp_out,
                                                  ull* __restrict__ Spack,
                                                  float* __restrict__ qtail,
                                                  float* __restrict__ ptail,
                                                  uint32_t kz0, uint32_t kz1) {
  __shared__ float red[4];
  int sb = blockIdx.x;
  int z = threadIdx.x;
  int b = sb & (NB - 1);
  uint32_t i = (uint32_t)sb * NZ + z;
  const uint32_t h = (uint32_t)SBTOT * NZ / 2;
  float u = tf_uniform(kz0, kz1, i, h);
  float qv = q[b * NZ + z];
  int smp = (u < qv) ? 1 : 0;
  samp_out[i] = (float)smp;
  ull m = __ballot(smp);
  if ((z & 63) == 0) Spack[sb * 4 + (z >> 6)] = m;
  float dq = (z >= NK && smp) ? d_lq[b * NZ + z] : 0.0f;
  float dp = (z >= NK && smp) ? d_lpz[z] : 0.0f;
  float sq = blockReduceSum256(dq, red);
  float sp = blockReduceSum256(dp, red);
  if (z == 0) { qtail[sb] = sq; ptail[sb] = sp; }
}

// ---------------- K3: base = samples @ V^T + x_bias; ps; xouts ----------------
__global__ __launch_bounds__(256) void k3_gemm(const float* __restrict__ samples,
                                               const float* __restrict__ V,
                                               const float* __restrict__ x_bias,
                                               float* __restrict__ base,
                                               float* __restrict__ ps_out,
                                               float* __restrict__ xo_out,
                                               uint32_t kx0, uint32_t kx1) {
  __shared__ float As[64][17];
  __shared__ float Bs[64][17];
  int tid = threadIdx.x;
  int tx = tid & 15, ty = tid >> 4;
  int x0 = blockIdx.x * 64;
  int sb0 = blockIdx.y * 64;
  int lr = tid >> 2;
  int lk = (tid & 3) << 2;
  float acc[4][4];
#pragma unroll
  for (int i = 0; i < 4; ++i)
#pragma unroll
    for (int j = 0; j < 4; ++j) acc[i][j] = 0.0f;

  for (int k0 = 0; k0 < NZ; k0 += 16) {
    float4 a4 = *(const float4*)(samples + (size_t)(sb0 + lr) * NZ + k0 + lk);
    float4 b4 = *(const float4*)(V + (size_t)(x0 + lr) * NZ + k0 + lk);
    As[lr][lk] = a4.x; As[lr][lk + 1] = a4.y; As[lr][lk + 2] = a4.z; As[lr][lk + 3] = a4.w;
    Bs[lr][lk] = b4.x; Bs[lr][lk + 1] = b4.y; Bs[lr][lk + 2] = b4.z; Bs[lr][lk + 3] = b4.w;
    __syncthreads();
#pragma unroll
    for (int kk = 0; kk < 16; ++kk) {
      float a_[4], b_[4];
#pragma unroll
      for (int i = 0; i < 4; ++i) a_[i] = As[ty * 4 + i][kk];
#pragma unroll
      for (int j = 0; j < 4; ++j) b_[j] = Bs[tx * 4 + j][kk];
#pragma unroll
      for (int i = 0; i < 4; ++i)
#pragma unroll
        for (int j = 0; j < 4; ++j) acc[i][j] += a_[i] * b_[j];
    }
    __syncthreads();
  }
  const uint32_t h = (uint32_t)SBTOT * NX / 2;
  float xb[4];
#pragma unroll
  for (int j = 0; j < 4; ++j) xb[j] = x_bias[x0 + tx * 4 + j];
#pragma unroll
  for (int i = 0; i < 4; ++i) {
    int sb = sb0 + ty * 4 + i;
    float bs[4], pv[4], xv[4];
#pragma unroll
    for (int j = 0; j < 4; ++j) {
      int x = x0 + tx * 4 + j;
      float a = acc[i][j] + xb[j];
      bs[j] = a;
      float p = sigclip(a);
      pv[j] = p;
      uint32_t fi = (uint32_t)sb * NX + x;
      float u = tf_uniform(kx0, kx1, fi, h);
      xv[j] = (u < p) ? 1.0f : 0.0f;
    }
    int off = sb * NX + x0 + tx * 4;
    *(float4*)(base + off) = make_float4(bs[0], bs[1], bs[2], bs[3]);
    *(float4*)(ps_out + off) = make_float4(pv[0], pv[1], pv[2], pv[3]);
    *(float4*)(xo_out + off) = make_float4(xv[0], xv[1], xv[2], xv[3]);
  }
}

// ---------------- KP: Vkpad[x][32] = bf16(V[x][k<25]), 0-padded ----------------
__global__ __launch_bounds__(256) void kP_vkpad(const float* __restrict__ V,
                                                ushort* __restrict__ Vkpad) {
  int e = blockIdx.x * 256 + threadIdx.x;  // < NX*32
  int x = e >> 5, k = e & 31;
  float v = (k < NK) ? V[(size_t)x * NZ + k] : 0.0f;
  uint32_t u = __float_as_uint(v);
  uint32_t r = (u + 0x7FFFu + ((u >> 16) & 1u)) >> 16;  // RNE f32->bf16
  Vkpad[e] = (ushort)r;
}

// ---------------- K4: GF(2) row reduce (parallel bit-gen + wave0 elimination) ----------------
__global__ __launch_bounds__(256) void k4_rowreduce(ull* __restrict__ Ct,
                                                    uint32_t* __restrict__ bpmask,
                                                    uint32_t kA0, uint32_t kA1,
                                                    uint32_t kb0, uint32_t kb1) {
  __shared__ uint32_t Aw[NK][8];
  __shared__ uint32_t bbsh[NK];
  int t = blockIdx.x;
  int tid = threadIdx.x;
  if (tid < NK * 8) {
    int r = tid >> 3, c = tid & 7;
    const uint32_t hA = (uint32_t)NT * NK * NZ / 2;
    uint32_t base_i = (uint32_t)(t * NK + r) * NZ + c * 32;
    uint32_t w = 0;
    for (int zz = 0; zz < 32; ++zz) {
      uint32_t rr = tf_select(kA0, kA1, base_i + zz, hA);
      w |= ((rr >> 31) ^ 1u) << zz;  // bit=1 iff u<0.5 (top bit 0)
    }
    Aw[r][c] = w;
  }
  if (tid < NK) {
    const uint32_t hb = (uint32_t)NT * NK / 2;
    uint32_t rb = tf_select(kb0, kb1, (uint32_t)(t * NK + tid), hb);
    bbsh[tid] = (rb >> 31) ^ 1u;
  }
  __syncthreads();
  if (tid >= 64) return;  // wave 0 does the elimination
  int lane = tid;
  ull w0 = 0, w1 = 0, w2 = 0, w3 = 0;
  uint32_t bbit = 0;
  if (lane < NK) {
    w0 = (ull)Aw[lane][0] | ((ull)Aw[lane][1] << 32);
    w1 = (ull)Aw[lane][2] | ((ull)Aw[lane][3] << 32);
    w2 = (ull)Aw[lane][4] | ((ull)Aw[lane][5] << 32);
    w3 = (ull)Aw[lane][6] | ((ull)Aw[lane][7] << 32);
    bbit = bbsh[lane];
  }
  for (int i = 0; i < NK; ++i) {
    int mybit = (int)((w0 >> i) & 1ull);
    ull mask = __ballot(lane < NK && mybit);
    ull cand = mask & (~0ull << i);
    int p = cand ? __builtin_ctzll(cand) : (NK - 1);
    int srcl = (lane == i) ? p : ((lane == p) ? i : lane);
    w0 = __shfl(w0, srcl); w1 = __shfl(w1, srcl); w2 = __shfl(w2, srcl); w3 = __shfl(w3, srcl);
    bbit = __shfl(bbit, srcl);
    ull p0 = __shfl(w0, i), p1 = __shfl(w1, i), p2 = __shfl(w2, i), p3 = __shfl(w3, i);
    uint32_t pvb = __shfl(bbit, i);
    int nb2 = (int)((w0 >> i) & 1ull);
    if (lane < NK && lane != i && nb2) {
      w0 ^= p0; w1 ^= p1; w2 ^= p2; w3 ^= p3; bbit ^= pvb;
    }
  }
  if (lane < NK) {
    w0 &= ~((1ull << NK) - 1ull);  // only columns z>=k feed proj
    ull* dstp = Ct + (size_t)(t * NK + lane) * 4;
    dstp[0] = w0; dstp[1] = w1; dstp[2] = w2; dstp[3] = w3;
  }
  ull bm = __ballot(lane < NK && bbit);
  if (lane == 0) bpmask[t] = (uint32_t)bm & 0x1FFFFFFu;
}

// ---------------- K5: proj bits, layout projb[sb*32 + t] (t>=NT -> s25 => d=0) -------
__global__ __launch_bounds__(256) void k5_proj(const ull* __restrict__ Spack,
                                               const ull* __restrict__ Ct,
                                               const uint32_t* __restrict__ bpmask,
                                               uint32_t* __restrict__ projb) {
  int e = blockIdx.x * 256 + threadIdx.x;  // < SBTOT*32
  int sb = e >> 5, t = e & 31;
  ull s0 = Spack[sb * 4 + 0], s1 = Spack[sb * 4 + 1];
  ull s2 = Spack[sb * 4 + 2], s3 = Spack[sb * 4 + 3];
  uint32_t out;
  if (t < NT) {
    uint32_t bp = bpmask[t];
    uint32_t pb = 0;
#pragma unroll
    for (int j = 0; j < NK; ++j) {
      const ull* C = Ct + (size_t)(t * NK + j) * 4;
      int par = __popcll(s0 & C[0]) + __popcll(s1 & C[1]) + __popcll(s2 & C[2]) + __popcll(s3 & C[3]);
      uint32_t bit = ((uint32_t)par ^ (bp >> j)) & 1u;
      pb |= bit << j;
    }
    out = pb;
  } else {
    out = (uint32_t)(s0 & 0x1FFFFFFull);  // d = pb - s25 = 0
  }
  projb[e] = out;
}

// ---------------- K6: logp_x via MFMA delta-GEMM + fused softplus reduce ----------------
// One block per sb. A = d[t][k] (32x32, bf16 in {-1,0,1}), B = Vk^T (32k x 16x tiles).
// delta[t,x] = sum_k d*Vk; a = base[sb,x] + delta; logpx[t,sb] = -sum_x softplus(+-a).
__global__ __launch_bounds__(256) void k6_mfma(const float* __restrict__ base,
                                               const ushort* __restrict__ Vkpad,
                                               const float* __restrict__ xin,
                                               const uint32_t* __restrict__ projb,
                                               const ull* __restrict__ Spack,
                                               float* __restrict__ logpx) {
  __shared__ float lsum[4][32];
  int sb = blockIdx.x;
  int b = sb & (NB - 1);
  int tid = threadIdx.x;
  int wave = tid >> 6, lane = tid & 63;
  int grp = lane >> 4, col = lane & 15;
  uint32_t s25 = (uint32_t)(Spack[sb * 4] & 0x1FFFFFFull);
  // A-frags: lane holds m=col (=t within tile), k = grp*8+j
  uint32_t pb0 = projb[sb * 32 + col];       // t = col
  uint32_t pb1 = projb[sb * 32 + 16 + col];  // t = 16+col (30,31 -> s25 -> d=0)
  bf16x8 a0, a1;
  union { ushort u; __bf16 h; } cvt;
#pragma unroll
  for (int j = 0; j < 8; ++j) {
    int k = grp * 8 + j;
    int sbit = (int)((s25 >> k) & 1u);
    int d0 = (int)((pb0 >> k) & 1u) - sbit;
    int d1 = (int)((pb1 >> k) & 1u) - sbit;
    cvt.u = (ushort)(d0 == 0 ? 0 : (d0 > 0 ? 0x3F80 : 0xBF80)); a0[j] = cvt.h;
    cvt.u = (ushort)(d1 == 0 ? 0 : (d1 > 0 ? 0x3F80 : 0xBF80)); a1[j] = cvt.h;
  }
  float acc[8];
#pragma unroll
  for (int r = 0; r < 8; ++r) acc[r] = 0.0f;
  const float* brow = base + (size_t)sb * NX;
  const float* xrow = xin + (size_t)b * NX;
#pragma unroll 1
  for (int i = 0; i < 32; ++i) {
    int x0 = (wave * 32 + i) * 16;
    int x = x0 + col;
    // B-frag: lane holds n=col, k=grp*8+j -> Vkpad[(x0+col)*32 + grp*8 ..+7]
    bf16x8 bfr = *(const bf16x8*)(Vkpad + (size_t)x * 32 + grp * 8);
    f32x4 c0 = {0.0f, 0.0f, 0.0f, 0.0f}, c1 = {0.0f, 0.0f, 0.0f, 0.0f};
    c0 = __builtin_amdgcn_mfma_f32_16x16x32_bf16(a0, bfr, c0, 0, 0, 0);
    c1 = __builtin_amdgcn_mfma_f32_16x16x32_bf16(a1, bfr, c1, 0, 0, 0);
    float bv = brow[x];
    uint32_t sm = (xrow[x] > 0.5f) ? 0x80000000u : 0u;
#pragma unroll
    for (int r = 0; r < 4; ++r) {
      acc[r] += sp_eval(bv + c0[r], sm);      // t = grp*4+r
      acc[4 + r] += sp_eval(bv + c1[r], sm);  // t = 16+grp*4+r
    }
  }
  // reduce over the 16 col-lanes within each row-group
#pragma unroll
  for (int r = 0; r < 8; ++r) {
#pragma unroll
    for (int off = 1; off < 16; off <<= 1) acc[r] += __shfl_xor(acc[r], off);
  }
  if (col == 0) {
#pragma unroll
    for (int r = 0; r < 4; ++r) {
      lsum[wave][grp * 4 + r] = acc[r];
      lsum[wave][16 + grp * 4 + r] = acc[4 + r];
    }
  }
  __syncthreads();
  if (tid < NT) {
    float tot = lsum[0][tid] + lsum[1][tid] + lsum[2][tid] + lsum[3][tid];
    logpx[(size_t)tid * SBTOT + sb] = -tot;
  }
}

// ---------------- K7: per-t weighted reduction over (s,b) ----------------
__global__ __launch_bounds__(512) void k7_reduce(const float* __restrict__ logpx,
                                                 const uint32_t* __restrict__ projb,
                                                 const float* __restrict__ qtail,
                                                 const float* __restrict__ ptail,
                                                 const float* __restrict__ baseq,
                                                 const float* __restrict__ d_lq,
                                                 const float* __restrict__ d_lpz,
                                                 const float* __restrict__ basepz,
                                                 double* __restrict__ pelbo) {
  __shared__ double red8[8];
  int t = blockIdx.x;
  int b = threadIdx.x;
  float dlq[NK];
#pragma unroll
  for (int j = 0; j < NK; ++j) dlq[j] = d_lq[b * NZ + j];
  float bq = baseq[b];
  float bpz = *basepz;
  float lq[NS], lp[NS];
#pragma unroll
  for (int s = 0; s < NS; ++s) {
    int sb = s * NB + b;
    uint32_t m = projb[sb * 32 + t];
    float sq = 0.0f, spv = 0.0f;
#pragma unroll
    for (int j = 0; j < NK; ++j) {
      float on = (float)((m >> j) & 1u);
      sq += on * dlq[j];
      spv += on * d_lpz[j];
    }
    lq[s] = bq + qtail[sb] + sq;
    lp[s] = logpx[t * SBTOT + sb] + bpz + ptail[sb] + spv;
  }
  float mx = lq[0];
#pragma unroll
  for (int s = 1; s < NS; ++s) mx = fmaxf(mx, lq[s]);
  float den = 0.0f, num = 0.0f;
#pragma unroll
  for (int s = 0; s < NS; ++s) {
    float w = __expf(lq[s] - mx);
    den += w;
    num += w * (lq[s] - lp[s]);
  }
  double v = (double)(num / den);
#pragma unroll
  for (int o = 32; o > 0; o >>= 1) v += __shfl_down(v, o);
  __syncthreads();
  if ((b & 63) == 0) red8[b >> 6] = v;
  __syncthreads();
  if (b == 0) {
    double s = 0.0;
    for (int i = 0; i < 8; ++i) s += red8[i];
    pelbo[t] = s;
  }
}

// ---------------- K8: final loss ----------------
__global__ __launch_bounds__(64) void k8_loss(const double* __restrict__ pelbo,
                                              float* __restrict__ out_loss) {
  int t = threadIdx.x;
  double v = (t < NT) ? pelbo[t] : 0.0;
#pragma unroll
  for (int o = 32; o > 0; o >>= 1) v += __shfl_down(v, o);
  if (t == 0) *out_loss = (float)(v / (double)NT);
}

extern "C" void kernel_launch(void* const* d_in, const int* in_sizes, int n_in,
                              void* d_out, int out_size, void* d_ws, size_t ws_size,
                              hipStream_t stream) {
  const float* xin = (const float*)d_in[0];
  const float* U = (const float*)d_in[1];
  const float* V = (const float*)d_in[2];
  const float* x_bias = (const float*)d_in[3];
  const float* z_bias = (const float*)d_in[4];
  float* out = (float*)d_out;

  char* p = (char*)d_ws;
  float* base = (float*)p;                p += (size_t)SBTOT * NX * 4;
  float* d_lq = (float*)p;                p += (size_t)NB * NZ * 4;
  float* baseq = (float*)p;               p += (size_t)NB * 4;
  float* d_lpz = (float*)p;               p += (size_t)NZ * 4;
  float* basepz = (float*)p;              p += 16;
  ull* Spack = (ull*)p;                   p += (size_t)SBTOT * 4 * 8;
  float* qtail = (float*)p;               p += (size_t)SBTOT * 4;
  float* ptail = (float*)p;               p += (size_t)SBTOT * 4;
  ull* Ct = (ull*)p;                      p += (size_t)NT * NK * 4 * 8;
  uint32_t* bpm = (uint32_t*)p;           p += 128;
  uint32_t* projb = (uint32_t*)p;         p += (size_t)SBTOT * 32 * 4;
  float* logpx = (float*)p;               p += (size_t)NT * SBTOT * 4;
  double* pelbo = (double*)p;             p += (size_t)NT * 8;
  ushort* Vkpad = (ushort*)p;             p += (size_t)NX * 32 * 2;
  (void)ws_size; (void)in_sizes; (void)n_in; (void)out_size;

  // JAX: key(42) -> split 4 -> kz,kx,kA,kb
  uint32_t o0[4], o1[4];
  for (int j = 0; j < 4; ++j) tf2x32(0u, 42u, (uint32_t)j, (uint32_t)(4 + j), o0[j], o1[j]);
  uint32_t kz0 = o0[0], kz1 = o0[1];
  uint32_t kx0 = o0[2], kx1 = o0[3];
  uint32_t kA0 = o1[0], kA1 = o1[1];
  uint32_t kb0 = o1[2], kb1 = o1[3];

  k0_pz<<<1, 256, 0, stream>>>(z_bias, d_lpz, basepz);
  k1_q<<<NB / K1_ROWS, 256, 0, stream>>>(xin, U, z_bias, out + OFF_Q, d_lq, baseq);
  k2_samples<<<SBTOT, 256, 0, stream>>>(out + OFF_Q, d_lq, d_lpz, out + OFF_SAMP,
                                        Spack, qtail, ptail, kz0, kz1);
  kP_vkpad<<<NX * 32 / 256, 256, 0, stream>>>(V, Vkpad);
  dim3 g3(NX / 64, SBTOT / 64);
  k3_gemm<<<g3, 256, 0, stream>>>(out + OFF_SAMP, V, x_bias, base,
                                  out + OFF_PS, out + OFF_XO, kx0, kx1);
  k4_rowreduce<<<NT, 256, 0, stream>>>(Ct, bpm, kA0, kA1, kb0, kb1);
  k5_proj<<<SBTOT * 32 / 256, 256, 0, stream>>>(Spack, Ct, bpm, projb);
  k6_mfma<<<SBTOT, 256, 0, stream>>>(base, Vkpad, xin, projb, Spack, logpx);
  k7_reduce<<<NT, 512, 0, stream>>>(logpx, projb, qtail, ptail, baseq, d_lq,
                                    d_lpz, basepz, pelbo);
  k8_loss<<<1, 64, 0, stream>>>(pelbo, out + OFF_LOSS);
}

// Round 3
// 377.838 us; speedup vs baseline: 3.4232x; 1.3852x over previous
//
#include <hip/hip_runtime.h>
#include <cstdint>

// Problem constants (setup_inputs fixed: nx=2048, nz=256, B=512, S=10, k=25, T=30)
#define NX 2048
#define NZ 256
#define NB 512
#define NS 10
#define NK 25
#define NT 30
#define SBTOT (NS * NB)  // 5120

#define LOG2E 1.4426950408889634f
#define LN2 0.6931471805599453f

// d_out flat layout (all float32): q, samples_z, ps, xouts, loss
#define OFF_Q 0
#define OFF_SAMP (NB * NZ)
#define OFF_PS (OFF_SAMP + SBTOT * NZ)
#define OFF_XO (OFF_PS + SBTOT * NX)
#define OFF_LOSS (OFF_XO + SBTOT * NX)

typedef unsigned long long ull;
typedef __bf16 bf16x8 __attribute__((ext_vector_type(8)));
typedef float f32x4 __attribute__((ext_vector_type(4)));

// ---------------- JAX Threefry-2x32 (exact) ----------------
__host__ __device__ inline void tf2x32(uint32_t k0, uint32_t k1, uint32_t x0, uint32_t x1,
                                       uint32_t& o0, uint32_t& o1) {
  uint32_t k2 = k0 ^ k1 ^ 0x1BD11BDAu;
  x0 += k0; x1 += k1;
#define TF_R(r) { x0 += x1; x1 = (x1 << (r)) | (x1 >> (32 - (r))); x1 ^= x0; }
  TF_R(13) TF_R(15) TF_R(26) TF_R(6)
  x0 += k1; x1 += k2 + 1u;
  TF_R(17) TF_R(29) TF_R(16) TF_R(24)
  x0 += k2; x1 += k0 + 2u;
  TF_R(13) TF_R(15) TF_R(26) TF_R(6)
  x0 += k0; x1 += k1 + 3u;
  TF_R(17) TF_R(29) TF_R(16) TF_R(24)
  x0 += k1; x1 += k2 + 4u;
  TF_R(13) TF_R(15) TF_R(26) TF_R(6)
  x0 += k2; x1 += k0 + 5u;
#undef TF_R
  o0 = x0; o1 = x1;
}

// JAX threefry over iota(n): element i (h=n/2): i<h -> o0(i,i+h); else o1(i-h,i)
__device__ inline uint32_t tf_select(uint32_t k0, uint32_t k1, uint32_t i, uint32_t h) {
  bool lo = i < h;
  uint32_t x0 = lo ? i : i - h;
  uint32_t x1 = lo ? i + h : i;
  uint32_t o0, o1;
  tf2x32(k0, k1, x0, x1, o0, o1);
  return lo ? o0 : o1;
}

__device__ inline float tf_uniform(uint32_t k0, uint32_t k1, uint32_t i, uint32_t h) {
  uint32_t r = tf_select(k0, k1, i, h);
  return __uint_as_float(0x3f800000u | (r >> 9)) - 1.0f;  // [0,1), exactly JAX
}

__device__ inline float sigclip(float a) {
  float p = 1.0f / (1.0f + __expf(-a));
  return fminf(fmaxf(p, 1e-6f), 1.0f - 1e-6f);
}

__device__ inline ushort f2bf(float f) {  // RNE f32->bf16 (no NaN inputs here)
  uint32_t u = __float_as_uint(f);
  return (ushort)((u + 0x7FFFu + ((u >> 16) & 1u)) >> 16);
}

__device__ inline float blockReduceSum256(float v, volatile float* s4) {
#pragma unroll
  for (int o = 32; o > 0; o >>= 1) v += __shfl_down(v, o);
  __syncthreads();
  if ((threadIdx.x & 63) == 0) s4[threadIdx.x >> 6] = v;
  __syncthreads();
  return s4[0] + s4[1] + s4[2] + s4[3];
}

// ---------------- KP0: Vbf (bf16 V), Vkpad2 (bf16 V[:, :25]*log2e padded), pz terms ----
__global__ __launch_bounds__(256) void kP0_prep(const float* __restrict__ V,
                                                const float* __restrict__ z_bias,
                                                ushort* __restrict__ Vbf,
                                                ushort* __restrict__ Vkpad2,
                                                float* __restrict__ d_lpz,
                                                float* __restrict__ basepz) {
  __shared__ float red[4];
  int e = blockIdx.x * 256 + threadIdx.x;  // < NX*NZ
  int x = e >> 8, k = e & 255;
  float v = V[e];
  Vbf[e] = f2bf(v);
  if (k < 32) Vkpad2[x * 32 + k] = (k < NK) ? f2bf(v * LOG2E) : (ushort)0;
  if (blockIdx.x == 0) {
    int z = threadIdx.x;
    float pz = sigclip(z_bias[z]);
    float lp = __logf(pz), l1 = __logf(1.0f - pz);
    d_lpz[z] = lp - l1;
    float s = blockReduceSum256(l1, red);
    if (z == 0) *basepz = s;
  }
}

// ---------------- K1: q = clip(sigmoid(xin @ U^T + z_bias)) ----------------
#define K1_ROWS 4
__global__ __launch_bounds__(256) void k1_q(const float* __restrict__ xin,
                                            const float* __restrict__ U,
                                            const float* __restrict__ z_bias,
                                            float* __restrict__ outq,
                                            float* __restrict__ d_lq,
                                            float* __restrict__ baseq) {
  __shared__ float xs[K1_ROWS][NX];
  __shared__ float red[4];
  int b0 = blockIdx.x * K1_ROWS;
  int tid = threadIdx.x;
  const float4* src = (const float4*)(xin + (size_t)b0 * NX);
  float4* dst = (float4*)(&xs[0][0]);
  for (int i = tid; i < K1_ROWS * NX / 4; i += 256) dst[i] = src[i];
  __syncthreads();
  int z = tid;
  float acc[K1_ROWS];
#pragma unroll
  for (int r = 0; r < K1_ROWS; ++r) acc[r] = 0.0f;
  const float4* U4 = (const float4*)(U + (size_t)z * NX);
  for (int i4 = 0; i4 < NX / 4; ++i4) {
    float4 u = U4[i4];
    int i = i4 * 4;
#pragma unroll
    for (int r = 0; r < K1_ROWS; ++r)
      acc[r] += u.x * xs[r][i] + u.y * xs[r][i + 1] + u.z * xs[r][i + 2] + u.w * xs[r][i + 3];
  }
  float zb = z_bias[z];
  for (int r = 0; r < K1_ROWS; ++r) {
    int b = b0 + r;
    float q = sigclip(acc[r] + zb);
    outq[b * NZ + z] = q;
    float lq = __logf(q), l1 = __logf(1.0f - q);
    d_lq[b * NZ + z] = lq - l1;
    float s = blockReduceSum256(l1, red);
    if (tid == 0) baseq[b] = s;
  }
}

// ---------------- K2: samples_z (f32 + bf16) + packed bits + tails ----------------
__global__ __launch_bounds__(256) void k2_samples(const float* __restrict__ q,
                                                  const float* __restrict__ d_lq,
                                                  const float* __restrict__ d_lpz,
                                                  float* __restrict__ samp_out,
                                                  ushort* __restrict__ samp16,
                                                  ull* __restrict__ Spack,
                                                  float* __restrict__ qtail,
                                                  float* __restrict__ ptail,
                                                  uint32_t kz0, uint32_t kz1) {
  __shared__ float red[4];
  int sb = blockIdx.x;
  int z = threadIdx.x;
  int b = sb & (NB - 1);
  uint32_t i = (uint32_t)sb * NZ + z;
  const uint32_t h = (uint32_t)SBTOT * NZ / 2;
  float u = tf_uniform(kz0, kz1, i, h);
  float qv = q[b * NZ + z];
  int smp = (u < qv) ? 1 : 0;
  samp_out[i] = (float)smp;
  samp16[i] = smp ? (ushort)0x3F80 : (ushort)0;
  ull m = __ballot(smp);
  if ((z & 63) == 0) Spack[sb * 4 + (z >> 6)] = m;
  float dq = (z >= NK && smp) ? d_lq[b * NZ + z] : 0.0f;
  float dp = (z >= NK && smp) ? d_lpz[z] : 0.0f;
  float sq = blockReduceSum256(dq, red);
  float sp = blockReduceSum256(dp, red);
  if (z == 0) { qtail[sb] = sq; ptail[sb] = sp; }
}

// ---------------- K3M: bf16 MFMA GEMM: a = samp @ V^T + x_bias ----------------
// Outputs: base2 = a*log2e (for k6), ps = sigclip(a), xouts = (u < ps).
__global__ __launch_bounds__(256) void k3m_gemm(const ushort* __restrict__ samp16,
                                                const ushort* __restrict__ Vbf,
                                                const float* __restrict__ x_bias,
                                                float* __restrict__ base2,
                                                float* __restrict__ ps_out,
                                                float* __restrict__ xo_out,
                                                uint32_t kx0, uint32_t kx1) {
  __shared__ __align__(16) ushort As[128 * 32];
  __shared__ __align__(16) ushort Bs[128 * 32];
  int tid = threadIdx.x;
  int wave = tid >> 6, lane = tid & 63, grp = lane >> 4, col = lane & 15;
  int wr = wave >> 1, wc = wave & 1;
  int n0 = blockIdx.x * 128, m0 = blockIdx.y * 128;
  f32x4 acc[4][4];
#pragma unroll
  for (int mi = 0; mi < 4; ++mi)
#pragma unroll
    for (int ni = 0; ni < 4; ++ni) acc[mi][ni] = (f32x4){0.f, 0.f, 0.f, 0.f};

  for (int k0 = 0; k0 < NZ; k0 += 32) {
#pragma unroll
    for (int c = tid; c < 512; c += 256) {
      int row = c >> 2, kc = (c & 3) << 3;
      *(uint4*)&As[row * 32 + kc] = *(const uint4*)&samp16[(size_t)(m0 + row) * NZ + k0 + kc];
      *(uint4*)&Bs[row * 32 + kc] = *(const uint4*)&Vbf[(size_t)(n0 + row) * NZ + k0 + kc];
    }
    __syncthreads();
    bf16x8 af[4], bfv[4];
#pragma unroll
    for (int mi = 0; mi < 4; ++mi)
      af[mi] = *(const bf16x8*)&As[(wr * 64 + mi * 16 + col) * 32 + grp * 8];
#pragma unroll
    for (int ni = 0; ni < 4; ++ni)
      bfv[ni] = *(const bf16x8*)&Bs[(wc * 64 + ni * 16 + col) * 32 + grp * 8];
#pragma unroll
    for (int mi = 0; mi < 4; ++mi)
#pragma unroll
      for (int ni = 0; ni < 4; ++ni)
        acc[mi][ni] = __builtin_amdgcn_mfma_f32_16x16x32_bf16(af[mi], bfv[ni], acc[mi][ni], 0, 0, 0);
    __syncthreads();
  }
  const uint32_t h = (uint32_t)SBTOT * NX / 2;
  float xb[4];
#pragma unroll
  for (int ni = 0; ni < 4; ++ni) xb[ni] = x_bias[n0 + wc * 64 + ni * 16 + col];
#pragma unroll
  for (int mi = 0; mi < 4; ++mi) {
#pragma unroll
    for (int r = 0; r < 4; ++r) {
      int sb = m0 + wr * 64 + mi * 16 + grp * 4 + r;
      size_t rowoff = (size_t)sb * NX;
#pragma unroll
      for (int ni = 0; ni < 4; ++ni) {
        int x = n0 + wc * 64 + ni * 16 + col;
        float a = acc[mi][ni][r] + xb[ni];
        base2[rowoff + x] = a * LOG2E;
        float p = sigclip(a);
        ps_out[rowoff + x] = p;
        float u = tf_uniform(kx0, kx1, (uint32_t)sb * NX + x, h);
        xo_out[rowoff + x] = (u < p) ? 1.0f : 0.0f;
      }
    }
  }
}

// ---------------- K4: GF(2) row reduce (parallel bit-gen + wave0 elimination) ----------------
__global__ __launch_bounds__(256) void k4_rowreduce(ull* __restrict__ Ct,
                                                    uint32_t* __restrict__ bpmask,
                                                    uint32_t kA0, uint32_t kA1,
                                                    uint32_t kb0, uint32_t kb1) {
  __shared__ uint32_t Aw[NK][8];
  __shared__ uint32_t bbsh[NK];
  int t = blockIdx.x;
  int tid = threadIdx.x;
  if (tid < NK * 8) {
    int r = tid >> 3, c = tid & 7;
    const uint32_t hA = (uint32_t)NT * NK * NZ / 2;
    uint32_t base_i = (uint32_t)(t * NK + r) * NZ + c * 32;
    uint32_t w = 0;
    for (int zz = 0; zz < 32; ++zz) {
      uint32_t rr = tf_select(kA0, kA1, base_i + zz, hA);
      w |= ((rr >> 31) ^ 1u) << zz;  // bit=1 iff u<0.5 (top bit 0)
    }
    Aw[r][c] = w;
  }
  if (tid < NK) {
    const uint32_t hb = (uint32_t)NT * NK / 2;
    uint32_t rb = tf_select(kb0, kb1, (uint32_t)(t * NK + tid), hb);
    bbsh[tid] = (rb >> 31) ^ 1u;
  }
  __syncthreads();
  if (tid >= 64) return;  // wave 0 does the elimination
  int lane = tid;
  ull w0 = 0, w1 = 0, w2 = 0, w3 = 0;
  uint32_t bbit = 0;
  if (lane < NK) {
    w0 = (ull)Aw[lane][0] | ((ull)Aw[lane][1] << 32);
    w1 = (ull)Aw[lane][2] | ((ull)Aw[lane][3] << 32);
    w2 = (ull)Aw[lane][4] | ((ull)Aw[lane][5] << 32);
    w3 = (ull)Aw[lane][6] | ((ull)Aw[lane][7] << 32);
    bbit = bbsh[lane];
  }
  for (int i = 0; i < NK; ++i) {
    int mybit = (int)((w0 >> i) & 1ull);
    ull mask = __ballot(lane < NK && mybit);
    ull cand = mask & (~0ull << i);
    int p = cand ? __builtin_ctzll(cand) : (NK - 1);
    int srcl = (lane == i) ? p : ((lane == p) ? i : lane);
    w0 = __shfl(w0, srcl); w1 = __shfl(w1, srcl); w2 = __shfl(w2, srcl); w3 = __shfl(w3, srcl);
    bbit = __shfl(bbit, srcl);
    ull p0 = __shfl(w0, i), p1 = __shfl(w1, i), p2 = __shfl(w2, i), p3 = __shfl(w3, i);
    uint32_t pvb = __shfl(bbit, i);
    int nb2 = (int)((w0 >> i) & 1ull);
    if (lane < NK && lane != i && nb2) {
      w0 ^= p0; w1 ^= p1; w2 ^= p2; w3 ^= p3; bbit ^= pvb;
    }
  }
  if (lane < NK) {
    w0 &= ~((1ull << NK) - 1ull);  // only columns z>=k feed proj
    ull* dstp = Ct + (size_t)(t * NK + lane) * 4;
    dstp[0] = w0; dstp[1] = w1; dstp[2] = w2; dstp[3] = w3;
  }
  ull bm = __ballot(lane < NK && bbit);
  if (lane == 0) bpmask[t] = (uint32_t)bm & 0x1FFFFFFu;
}

// ---------------- K5: proj bits, layout projb[sb*32 + t] (t>=NT -> s25 => d=0) -------
__global__ __launch_bounds__(256) void k5_proj(const ull* __restrict__ Spack,
                                               const ull* __restrict__ Ct,
                                               const uint32_t* __restrict__ bpmask,
                                               uint32_t* __restrict__ projb) {
  int e = blockIdx.x * 256 + threadIdx.x;  // < SBTOT*32
  int sb = e >> 5, t = e & 31;
  ull s0 = Spack[sb * 4 + 0], s1 = Spack[sb * 4 + 1];
  ull s2 = Spack[sb * 4 + 2], s3 = Spack[sb * 4 + 3];
  uint32_t out;
  if (t < NT) {
    uint32_t bp = bpmask[t];
    uint32_t pb = 0;
#pragma unroll
    for (int j = 0; j < NK; ++j) {
      const ull* C = Ct + (size_t)(t * NK + j) * 4;
      int par = __popcll(s0 & C[0]) + __popcll(s1 & C[1]) + __popcll(s2 & C[2]) + __popcll(s3 & C[3]);
      uint32_t bit = ((uint32_t)par ^ (bp >> j)) & 1u;
      pb |= bit << j;
    }
    out = pb;
  } else {
    out = (uint32_t)(s0 & 0x1FFFFFFull);  // d = pb - s25 = 0
  }
  projb[e] = out;
}

// ---------------- K6: logp_x via MFMA delta-GEMM + fused softplus (log2-space) ----------
// y2 = log2e*(base + delta); softplus = ln2*(max(y2,0) + log2(1+2^-|y2|)).
// max via (y+|y|)/2 accumulators; log2 via running product pp *= (1+e), log2 once/32.
__global__ __launch_bounds__(256) void k6_mfma(const float* __restrict__ base2,
                                               const ushort* __restrict__ Vkpad2,
                                               const float* __restrict__ xin,
                                               const uint32_t* __restrict__ projb,
                                               const ull* __restrict__ Spack,
                                               float* __restrict__ logpx) {
  __shared__ float2 bvsm[NX];  // {base2, signf} per x — 16 KB
  __shared__ float lsum[4][32];
  int sb = blockIdx.x;
  int b = sb & (NB - 1);
  int tid = threadIdx.x;
  int wave = tid >> 6, lane = tid & 63;
  int grp = lane >> 4, col = lane & 15;
  // stage base2 row + sign row (coalesced float4)
  const float4* b4p = (const float4*)(base2 + (size_t)sb * NX);
  const float4* x4p = (const float4*)(xin + (size_t)b * NX);
#pragma unroll
  for (int i = tid; i < NX / 4; i += 256) {
    float4 bv = b4p[i];
    float4 xv = x4p[i];
    bvsm[i * 4 + 0] = make_float2(bv.x, 1.0f - 2.0f * xv.x);
    bvsm[i * 4 + 1] = make_float2(bv.y, 1.0f - 2.0f * xv.y);
    bvsm[i * 4 + 2] = make_float2(bv.z, 1.0f - 2.0f * xv.z);
    bvsm[i * 4 + 3] = make_float2(bv.w, 1.0f - 2.0f * xv.w);
  }
  // A-frags: lane holds m=col (t within tile), k = grp*8+j
  uint32_t s25 = (uint32_t)(Spack[sb * 4] & 0x1FFFFFFull);
  uint32_t pb0 = projb[sb * 32 + col];
  uint32_t pb1 = projb[sb * 32 + 16 + col];
  bf16x8 a0, a1;
  union { ushort u; __bf16 hh; } cvt;
#pragma unroll
  for (int j = 0; j < 8; ++j) {
    int k = grp * 8 + j;
    int sbit = (int)((s25 >> k) & 1u);
    int d0 = (int)((pb0 >> k) & 1u) - sbit;
    int d1 = (int)((pb1 >> k) & 1u) - sbit;
    cvt.u = (ushort)(d0 == 0 ? 0 : (d0 > 0 ? 0x3F80 : 0xBF80)); a0[j] = cvt.hh;
    cvt.u = (ushort)(d1 == 0 ? 0 : (d1 > 0 ? 0x3F80 : 0xBF80)); a1[j] = cvt.hh;
  }
  __syncthreads();
  float accy[8], acca[8], pp[8];
#pragma unroll
  for (int r = 0; r < 8; ++r) { accy[r] = 0.0f; acca[r] = 0.0f; pp[r] = 1.0f; }
  const ushort* vkbase = Vkpad2 + (size_t)(wave * 512 + col) * 32 + grp * 8;
#pragma unroll 2
  for (int i = 0; i < 32; ++i) {
    int x = (wave * 32 + i) * 16 + col;
    bf16x8 bfr = *(const bf16x8*)(vkbase + (size_t)i * 16 * 32);
    f32x4 c0 = {0.f, 0.f, 0.f, 0.f}, c1 = {0.f, 0.f, 0.f, 0.f};
    c0 = __builtin_amdgcn_mfma_f32_16x16x32_bf16(a0, bfr, c0, 0, 0, 0);
    c1 = __builtin_amdgcn_mfma_f32_16x16x32_bf16(a1, bfr, c1, 0, 0, 0);
    float2 bs = bvsm[x];
#pragma unroll
    for (int r = 0; r < 4; ++r) {
      float y0 = bs.x + c0[r];
      accy[r] = fmaf(bs.y, y0, accy[r]);
      acca[r] += fabsf(y0);
      float e0 = exp2f(-fabsf(y0));
      pp[r] = fmaf(pp[r], e0, pp[r]);
      float y1 = bs.x + c1[r];
      accy[4 + r] = fmaf(bs.y, y1, accy[4 + r]);
      acca[4 + r] += fabsf(y1);
      float e1 = exp2f(-fabsf(y1));
      pp[4 + r] = fmaf(pp[4 + r], e1, pp[4 + r]);
    }
  }
#pragma unroll
  for (int r = 0; r < 8; ++r) {
    float m = 0.5f * (accy[r] + acca[r]) + __log2f(pp[r]);
#pragma unroll
    for (int off = 1; off < 16; off <<= 1) m += __shfl_xor(m, off);
    if (col == 0) {
      int t = (r < 4) ? (grp * 4 + r) : (16 + grp * 4 + (r - 4));
      lsum[wave][t] = m;
    }
  }
  __syncthreads();
  if (tid < NT) {
    float tot = lsum[0][tid] + lsum[1][tid] + lsum[2][tid] + lsum[3][tid];
    logpx[(size_t)tid * SBTOT + sb] = -LN2 * tot;
  }
}

// ---------------- K7: per-t weighted reduction over (s,b) ----------------
__global__ __launch_bounds__(512) void k7_reduce(const float* __restrict__ logpx,
                                                 const uint32_t* __restrict__ projb,
                                                 const float* __restrict__ qtail,
                                                 const float* __restrict__ ptail,
                                                 const float* __restrict__ baseq,
                                                 const float* __restrict__ d_lq,
                                                 const float* __restrict__ d_lpz,
                                                 const float* __restrict__ basepz,
                                                 double* __restrict__ pelbo) {
  __shared__ double red8[8];
  int t = blockIdx.x;
  int b = threadIdx.x;
  float dlq[NK];
#pragma unroll
  for (int j = 0; j < NK; ++j) dlq[j] = d_lq[b * NZ + j];
  float bq = baseq[b];
  float bpz = *basepz;
  float lq[NS], lp[NS];
#pragma unroll
  for (int s = 0; s < NS; ++s) {
    int sb = s * NB + b;
    uint32_t m = projb[sb * 32 + t];
    float sq = 0.0f, spv = 0.0f;
#pragma unroll
    for (int j = 0; j < NK; ++j) {
      float on = (float)((m >> j) & 1u);
      sq += on * dlq[j];
      spv += on * d_lpz[j];
    }
    lq[s] = bq + qtail[sb] + sq;
    lp[s] = logpx[t * SBTOT + sb] + bpz + ptail[sb] + spv;
  }
  float mx = lq[0];
#pragma unroll
  for (int s = 1; s < NS; ++s) mx = fmaxf(mx, lq[s]);
  float den = 0.0f, num = 0.0f;
#pragma unroll
  for (int s = 0; s < NS; ++s) {
    float w = __expf(lq[s] - mx);
    den += w;
    num += w * (lq[s] - lp[s]);
  }
  double v = (double)(num / den);
#pragma unroll
  for (int o = 32; o > 0; o >>= 1) v += __shfl_down(v, o);
  __syncthreads();
  if ((b & 63) == 0) red8[b >> 6] = v;
  __syncthreads();
  if (b == 0) {
    double s = 0.0;
    for (int i = 0; i < 8; ++i) s += red8[i];
    pelbo[t] = s;
  }
}

// ---------------- K8: final loss ----------------
__global__ __launch_bounds__(64) void k8_loss(const double* __restrict__ pelbo,
                                              float* __restrict__ out_loss) {
  int t = threadIdx.x;
  double v = (t < NT) ? pelbo[t] : 0.0;
#pragma unroll
  for (int o = 32; o > 0; o >>= 1) v += __shfl_down(v, o);
  if (t == 0) *out_loss = (float)(v / (double)NT);
}

extern "C" void kernel_launch(void* const* d_in, const int* in_sizes, int n_in,
                              void* d_out, int out_size, void* d_ws, size_t ws_size,
                              hipStream_t stream) {
  const float* xin = (const float*)d_in[0];
  const float* U = (const float*)d_in[1];
  const float* V = (const float*)d_in[2];
  const float* x_bias = (const float*)d_in[3];
  const float* z_bias = (const float*)d_in[4];
  float* out = (float*)d_out;

  char* p = (char*)d_ws;
  float* base2 = (float*)p;               p += (size_t)SBTOT * NX * 4;
  float* d_lq = (float*)p;                p += (size_t)NB * NZ * 4;
  float* baseq = (float*)p;               p += (size_t)NB * 4;
  float* d_lpz = (float*)p;               p += (size_t)NZ * 4;
  float* basepz = (float*)p;              p += 16;
  ull* Spack = (ull*)p;                   p += (size_t)SBTOT * 4 * 8;
  float* qtail = (float*)p;               p += (size_t)SBTOT * 4;
  float* ptail = (float*)p;               p += (size_t)SBTOT * 4;
  ull* Ct = (ull*)p;                      p += (size_t)NT * NK * 4 * 8;
  uint32_t* bpm = (uint32_t*)p;           p += 128;
  uint32_t* projb = (uint32_t*)p;         p += (size_t)SBTOT * 32 * 4;
  float* logpx = (float*)p;               p += (size_t)NT * SBTOT * 4;
  double* pelbo = (double*)p;             p += (size_t)NT * 8;
  ushort* Vkpad2 = (ushort*)p;            p += (size_t)NX * 32 * 2;
  ushort* Vbf = (ushort*)p;               p += (size_t)NX * NZ * 2;
  ushort* samp16 = (ushort*)p;            p += (size_t)SBTOT * NZ * 2;
  (void)ws_size; (void)in_sizes; (void)n_in; (void)out_size;

  // JAX: key(42) -> split 4 -> kz,kx,kA,kb
  uint32_t o0[4], o1[4];
  for (int j = 0; j < 4; ++j) tf2x32(0u, 42u, (uint32_t)j, (uint32_t)(4 + j), o0[j], o1[j]);
  uint32_t kz0 = o0[0], kz1 = o0[1];
  uint32_t kx0 = o0[2], kx1 = o0[3];
  uint32_t kA0 = o1[0], kA1 = o1[1];
  uint32_t kb0 = o1[2], kb1 = o1[3];

  kP0_prep<<<NX * NZ / 256, 256, 0, stream>>>(V, z_bias, Vbf, Vkpad2, d_lpz, basepz);
  k1_q<<<NB / K1_ROWS, 256, 0, stream>>>(xin, U, z_bias, out + OFF_Q, d_lq, baseq);
  k4_rowreduce<<<NT, 256, 0, stream>>>(Ct, bpm, kA0, kA1, kb0, kb1);
  k2_samples<<<SBTOT, 256, 0, stream>>>(out + OFF_Q, d_lq, d_lpz, out + OFF_SAMP,
                                        samp16, Spack, qtail, ptail, kz0, kz1);
  dim3 g3(NX / 128, SBTOT / 128);
  k3m_gemm<<<g3, 256, 0, stream>>>(samp16, Vbf, x_bias, base2,
                                   out + OFF_PS, out + OFF_XO, kx0, kx1);
  k5_proj<<<SBTOT * 32 / 256, 256, 0, stream>>>(Spack, Ct, bpm, projb);
  k6_mfma<<<SBTOT, 256, 0, stream>>>(base2, Vkpad2, xin, projb, Spack, logpx);
  k7_reduce<<<NT, 512, 0, stream>>>(logpx, projb, qtail, ptail, baseq, d_lq,
                                    d_lpz, basepz, pelbo);
  k8_loss<<<1, 64, 0, stream>>>(pelbo, out + OFF_LOSS);
}

// Round 4
// 363.824 us; speedup vs baseline: 3.5551x; 1.0385x over previous
//
#include <hip/hip_runtime.h>
#include <cstdint>

// Problem constants (setup_inputs fixed: nx=2048, nz=256, B=512, S=10, k=25, T=30)
#define NX 2048
#define NZ 256
#define NB 512
#define NS 10
#define NK 25
#define NT 30
#define SBTOT (NS * NB)  // 5120

#define LOG2E 1.4426950408889634f
#define LN2 0.6931471805599453f

// d_out flat layout (all float32): q, samples_z, ps, xouts, loss
#define OFF_Q 0
#define OFF_SAMP (NB * NZ)
#define OFF_PS (OFF_SAMP + SBTOT * NZ)
#define OFF_XO (OFF_PS + SBTOT * NX)
#define OFF_LOSS (OFF_XO + SBTOT * NX)

typedef unsigned long long ull;
typedef __bf16 bf16x8 __attribute__((ext_vector_type(8)));
typedef float f32x4 __attribute__((ext_vector_type(4)));

// ---------------- JAX Threefry-2x32 (exact) ----------------
__host__ __device__ inline void tf2x32(uint32_t k0, uint32_t k1, uint32_t x0, uint32_t x1,
                                       uint32_t& o0, uint32_t& o1) {
  uint32_t k2 = k0 ^ k1 ^ 0x1BD11BDAu;
  x0 += k0; x1 += k1;
#define TF_R(r) { x0 += x1; x1 = (x1 << (r)) | (x1 >> (32 - (r))); x1 ^= x0; }
  TF_R(13) TF_R(15) TF_R(26) TF_R(6)
  x0 += k1; x1 += k2 + 1u;
  TF_R(17) TF_R(29) TF_R(16) TF_R(24)
  x0 += k2; x1 += k0 + 2u;
  TF_R(13) TF_R(15) TF_R(26) TF_R(6)
  x0 += k0; x1 += k1 + 3u;
  TF_R(17) TF_R(29) TF_R(16) TF_R(24)
  x0 += k1; x1 += k2 + 4u;
  TF_R(13) TF_R(15) TF_R(26) TF_R(6)
  x0 += k2; x1 += k0 + 5u;
#undef TF_R
  o0 = x0; o1 = x1;
}

// JAX threefry over iota(n): element i (h=n/2): i<h -> o0(i,i+h); else o1(i-h,i)
__device__ inline uint32_t tf_select(uint32_t k0, uint32_t k1, uint32_t i, uint32_t h) {
  bool lo = i < h;
  uint32_t x0 = lo ? i : i - h;
  uint32_t x1 = lo ? i + h : i;
  uint32_t o0, o1;
  tf2x32(k0, k1, x0, x1, o0, o1);
  return lo ? o0 : o1;
}

__device__ inline float tf_uniform(uint32_t k0, uint32_t k1, uint32_t i, uint32_t h) {
  uint32_t r = tf_select(k0, k1, i, h);
  return __uint_as_float(0x3f800000u | (r >> 9)) - 1.0f;  // [0,1), exactly JAX
}

__device__ inline float sigclip(float a) {
  float p = 1.0f / (1.0f + __expf(-a));
  return fminf(fmaxf(p, 1e-6f), 1.0f - 1e-6f);
}

__device__ inline ushort f2bf(float f) {  // RNE f32->bf16 (no NaN inputs here)
  uint32_t u = __float_as_uint(f);
  return (ushort)((u + 0x7FFFu + ((u >> 16) & 1u)) >> 16);
}

__device__ inline float blockReduceSum256(float v, volatile float* s4) {
#pragma unroll
  for (int o = 32; o > 0; o >>= 1) v += __shfl_down(v, o);
  __syncthreads();
  if ((threadIdx.x & 63) == 0) s4[threadIdx.x >> 6] = v;
  __syncthreads();
  return s4[0] + s4[1] + s4[2] + s4[3];
}

// ---------------- KP0: Vbf (bf16 V), Vkpad2 (bf16 V[:, :25]*log2e padded), pz terms ----
__global__ __launch_bounds__(256) void kP0_prep(const float* __restrict__ V,
                                                const float* __restrict__ z_bias,
                                                ushort* __restrict__ Vbf,
                                                ushort* __restrict__ Vkpad2,
                                                float* __restrict__ d_lpz,
                                                float* __restrict__ basepz) {
  __shared__ float red[4];
  int e = blockIdx.x * 256 + threadIdx.x;  // < NX*NZ
  int x = e >> 8, k = e & 255;
  float v = V[e];
  Vbf[e] = f2bf(v);
  if (k < 32) Vkpad2[x * 32 + k] = (k < NK) ? f2bf(v * LOG2E) : (ushort)0;
  if (blockIdx.x == 0) {
    int z = threadIdx.x;
    float pz = sigclip(z_bias[z]);
    float lp = __logf(pz), l1 = __logf(1.0f - pz);
    d_lpz[z] = lp - l1;
    float s = blockReduceSum256(l1, red);
    if (z == 0) *basepz = s;
  }
}

// ---------------- KW: W[b][k] = sum_x (1-2*xin[b,x]) * bf16val(Vkpad2[x,k]) ----------
__global__ __launch_bounds__(256) void kW_signdot(const float* __restrict__ xin,
                                                  const ushort* __restrict__ Vkpad2,
                                                  float* __restrict__ W) {
  __shared__ float wred[4][NK];
  int b = blockIdx.x;
  int tid = threadIdx.x;
  float acc[NK];
#pragma unroll
  for (int j = 0; j < NK; ++j) acc[j] = 0.0f;
#pragma unroll
  for (int i = 0; i < 8; ++i) {
    int x = i * 256 + tid;
    float s = 1.0f - 2.0f * xin[(size_t)b * NX + x];
    const uint4* vp = (const uint4*)(Vkpad2 + (size_t)x * 32);
    uint4 q0 = vp[0], q1 = vp[1], q2 = vp[2], q3 = vp[3];
    uint32_t w[16] = {q0.x, q0.y, q0.z, q0.w, q1.x, q1.y, q1.z, q1.w,
                      q2.x, q2.y, q2.z, q2.w, q3.x, q3.y, q3.z, q3.w};
#pragma unroll
    for (int j = 0; j < NK; ++j) {
      uint32_t wd = w[j >> 1];
      float v = __uint_as_float((j & 1) ? (wd & 0xFFFF0000u) : (wd << 16));
      acc[j] = fmaf(s, v, acc[j]);
    }
  }
#pragma unroll
  for (int j = 0; j < NK; ++j) {
#pragma unroll
    for (int o = 1; o < 64; o <<= 1) acc[j] += __shfl_xor(acc[j], o);
  }
  if ((tid & 63) == 0) {
#pragma unroll
    for (int j = 0; j < NK; ++j) wred[tid >> 6][j] = acc[j];
  }
  __syncthreads();
  if (tid < NK) W[b * 32 + tid] = wred[0][tid] + wred[1][tid] + wred[2][tid] + wred[3][tid];
}

// ---------------- K1: q = clip(sigmoid(xin @ U^T + z_bias)) ----------------
#define K1_ROWS 4
__global__ __launch_bounds__(256) void k1_q(const float* __restrict__ xin,
                                            const float* __restrict__ U,
                                            const float* __restrict__ z_bias,
                                            float* __restrict__ outq,
                                            float* __restrict__ d_lq,
                                            float* __restrict__ baseq) {
  __shared__ float xs[K1_ROWS][NX];
  __shared__ float red[4];
  int b0 = blockIdx.x * K1_ROWS;
  int tid = threadIdx.x;
  const float4* src = (const float4*)(xin + (size_t)b0 * NX);
  float4* dst = (float4*)(&xs[0][0]);
  for (int i = tid; i < K1_ROWS * NX / 4; i += 256) dst[i] = src[i];
  __syncthreads();
  int z = tid;
  float acc[K1_ROWS];
#pragma unroll
  for (int r = 0; r < K1_ROWS; ++r) acc[r] = 0.0f;
  const float4* U4 = (const float4*)(U + (size_t)z * NX);
  for (int i4 = 0; i4 < NX / 4; ++i4) {
    float4 u = U4[i4];
    int i = i4 * 4;
#pragma unroll
    for (int r = 0; r < K1_ROWS; ++r)
      acc[r] += u.x * xs[r][i] + u.y * xs[r][i + 1] + u.z * xs[r][i + 2] + u.w * xs[r][i + 3];
  }
  float zb = z_bias[z];
  for (int r = 0; r < K1_ROWS; ++r) {
    int b = b0 + r;
    float q = sigclip(acc[r] + zb);
    outq[b * NZ + z] = q;
    float lq = __logf(q), l1 = __logf(1.0f - q);
    d_lq[b * NZ + z] = lq - l1;
    float s = blockReduceSum256(l1, red);
    if (tid == 0) baseq[b] = s;
  }
}

// ---------------- K2: samples_z (f32 + bf16) + packed bits + tails ----------------
__global__ __launch_bounds__(256) void k2_samples(const float* __restrict__ q,
                                                  const float* __restrict__ d_lq,
                                                  const float* __restrict__ d_lpz,
                                                  float* __restrict__ samp_out,
                                                  ushort* __restrict__ samp16,
                                                  ull* __restrict__ Spack,
                                                  float* __restrict__ qtail,
                                                  float* __restrict__ ptail,
                                                  uint32_t kz0, uint32_t kz1) {
  __shared__ float red[4];
  int sb = blockIdx.x;
  int z = threadIdx.x;
  int b = sb & (NB - 1);
  uint32_t i = (uint32_t)sb * NZ + z;
  const uint32_t h = (uint32_t)SBTOT * NZ / 2;
  float u = tf_uniform(kz0, kz1, i, h);
  float qv = q[b * NZ + z];
  int smp = (u < qv) ? 1 : 0;
  samp_out[i] = (float)smp;
  samp16[i] = smp ? (ushort)0x3F80 : (ushort)0;
  ull m = __ballot(smp);
  if ((z & 63) == 0) Spack[sb * 4 + (z >> 6)] = m;
  float dq = (z >= NK && smp) ? d_lq[b * NZ + z] : 0.0f;
  float dp = (z >= NK && smp) ? d_lpz[z] : 0.0f;
  float sq = blockReduceSum256(dq, red);
  float sp = blockReduceSum256(dp, red);
  if (z == 0) { qtail[sb] = sq; ptail[sb] = sp; }
}

// ---------------- K3M: bf16 MFMA GEMM: a = samp @ V^T + x_bias ----------------
// Outputs: base2 (bf16, = a*log2e for k6), ps = sigclip(a), xouts = (u < ps).
__global__ __launch_bounds__(256) void k3m_gemm(const ushort* __restrict__ samp16,
                                                const ushort* __restrict__ Vbf,
                                                const float* __restrict__ x_bias,
                                                ushort* __restrict__ base2,
                                                float* __restrict__ ps_out,
                                                float* __restrict__ xo_out,
                                                uint32_t kx0, uint32_t kx1) {
  __shared__ __align__(16) ushort As[128 * 32];
  __shared__ __align__(16) ushort Bs[128 * 32];
  int tid = threadIdx.x;
  int wave = tid >> 6, lane = tid & 63, grp = lane >> 4, col = lane & 15;
  int wr = wave >> 1, wc = wave & 1;
  int n0 = blockIdx.x * 128, m0 = blockIdx.y * 128;
  f32x4 acc[4][4];
#pragma unroll
  for (int mi = 0; mi < 4; ++mi)
#pragma unroll
    for (int ni = 0; ni < 4; ++ni) acc[mi][ni] = (f32x4){0.f, 0.f, 0.f, 0.f};

  for (int k0 = 0; k0 < NZ; k0 += 32) {
#pragma unroll
    for (int c = tid; c < 512; c += 256) {
      int row = c >> 2, kc = (c & 3) << 3;
      *(uint4*)&As[row * 32 + kc] = *(const uint4*)&samp16[(size_t)(m0 + row) * NZ + k0 + kc];
      *(uint4*)&Bs[row * 32 + kc] = *(const uint4*)&Vbf[(size_t)(n0 + row) * NZ + k0 + kc];
    }
    __syncthreads();
    bf16x8 af[4], bfv[4];
#pragma unroll
    for (int mi = 0; mi < 4; ++mi)
      af[mi] = *(const bf16x8*)&As[(wr * 64 + mi * 16 + col) * 32 + grp * 8];
#pragma unroll
    for (int ni = 0; ni < 4; ++ni)
      bfv[ni] = *(const bf16x8*)&Bs[(wc * 64 + ni * 16 + col) * 32 + grp * 8];
#pragma unroll
    for (int mi = 0; mi < 4; ++mi)
#pragma unroll
      for (int ni = 0; ni < 4; ++ni)
        acc[mi][ni] = __builtin_amdgcn_mfma_f32_16x16x32_bf16(af[mi], bfv[ni], acc[mi][ni], 0, 0, 0);
    __syncthreads();
  }
  const uint32_t h = (uint32_t)SBTOT * NX / 2;
  float xb[4];
#pragma unroll
  for (int ni = 0; ni < 4; ++ni) xb[ni] = x_bias[n0 + wc * 64 + ni * 16 + col];
#pragma unroll
  for (int mi = 0; mi < 4; ++mi) {
#pragma unroll
    for (int r = 0; r < 4; ++r) {
      int sb = m0 + wr * 64 + mi * 16 + grp * 4 + r;
      size_t rowoff = (size_t)sb * NX;
#pragma unroll
      for (int ni = 0; ni < 4; ++ni) {
        int x = n0 + wc * 64 + ni * 16 + col;
        float a = acc[mi][ni][r] + xb[ni];
        base2[rowoff + x] = f2bf(a * LOG2E);
        float p = sigclip(a);
        ps_out[rowoff + x] = p;
        float u = tf_uniform(kx0, kx1, (uint32_t)sb * NX + x, h);
        xo_out[rowoff + x] = (u < p) ? 1.0f : 0.0f;
      }
    }
  }
}

// ---------------- K4: GF(2) row reduce (parallel bit-gen + wave0 elimination) ----------------
__global__ __launch_bounds__(256) void k4_rowreduce(ull* __restrict__ Ct,
                                                    uint32_t* __restrict__ bpmask,
                                                    uint32_t kA0, uint32_t kA1,
                                                    uint32_t kb0, uint32_t kb1) {
  __shared__ uint32_t Aw[NK][8];
  __shared__ uint32_t bbsh[NK];
  int t = blockIdx.x;
  int tid = threadIdx.x;
  if (tid < NK * 8) {
    int r = tid >> 3, c = tid & 7;
    const uint32_t hA = (uint32_t)NT * NK * NZ / 2;
    uint32_t base_i = (uint32_t)(t * NK + r) * NZ + c * 32;
    uint32_t w = 0;
    for (int zz = 0; zz < 32; ++zz) {
      uint32_t rr = tf_select(kA0, kA1, base_i + zz, hA);
      w |= ((rr >> 31) ^ 1u) << zz;  // bit=1 iff u<0.5 (top bit 0)
    }
    Aw[r][c] = w;
  }
  if (tid < NK) {
    const uint32_t hb = (uint32_t)NT * NK / 2;
    uint32_t rb = tf_select(kb0, kb1, (uint32_t)(t * NK + tid), hb);
    bbsh[tid] = (rb >> 31) ^ 1u;
  }
  __syncthreads();
  if (tid >= 64) return;  // wave 0 does the elimination
  int lane = tid;
  ull w0 = 0, w1 = 0, w2 = 0, w3 = 0;
  uint32_t bbit = 0;
  if (lane < NK) {
    w0 = (ull)Aw[lane][0] | ((ull)Aw[lane][1] << 32);
    w1 = (ull)Aw[lane][2] | ((ull)Aw[lane][3] << 32);
    w2 = (ull)Aw[lane][4] | ((ull)Aw[lane][5] << 32);
    w3 = (ull)Aw[lane][6] | ((ull)Aw[lane][7] << 32);
    bbit = bbsh[lane];
  }
  for (int i = 0; i < NK; ++i) {
    int mybit = (int)((w0 >> i) & 1ull);
    ull mask = __ballot(lane < NK && mybit);
    ull cand = mask & (~0ull << i);
    int p = cand ? __builtin_ctzll(cand) : (NK - 1);
    int srcl = (lane == i) ? p : ((lane == p) ? i : lane);
    w0 = __shfl(w0, srcl); w1 = __shfl(w1, srcl); w2 = __shfl(w2, srcl); w3 = __shfl(w3, srcl);
    bbit = __shfl(bbit, srcl);
    ull p0 = __shfl(w0, i), p1 = __shfl(w1, i), p2 = __shfl(w2, i), p3 = __shfl(w3, i);
    uint32_t pvb = __shfl(bbit, i);
    int nb2 = (int)((w0 >> i) & 1ull);
    if (lane < NK && lane != i && nb2) {
      w0 ^= p0; w1 ^= p1; w2 ^= p2; w3 ^= p3; bbit ^= pvb;
    }
  }
  if (lane < NK) {
    w0 &= ~((1ull << NK) - 1ull);  // only columns z>=k feed proj
    ull* dstp = Ct + (size_t)(t * NK + lane) * 4;
    dstp[0] = w0; dstp[1] = w1; dstp[2] = w2; dstp[3] = w3;
  }
  ull bm = __ballot(lane < NK && bbit);
  if (lane == 0) bpmask[t] = (uint32_t)bm & 0x1FFFFFFu;
}

// ---------------- K5: proj bits + Syd = sum_j d_j*W[b,j]; layout [sb*32+t] -------
__global__ __launch_bounds__(256) void k5_proj(const ull* __restrict__ Spack,
                                               const ull* __restrict__ Ct,
                                               const uint32_t* __restrict__ bpmask,
                                               const float* __restrict__ W,
                                               uint32_t* __restrict__ projb,
                                               float* __restrict__ Syd) {
  int e = blockIdx.x * 256 + threadIdx.x;  // < SBTOT*32
  int sb = e >> 5, t = e & 31;
  ull s0 = Spack[sb * 4 + 0], s1 = Spack[sb * 4 + 1];
  ull s2 = Spack[sb * 4 + 2], s3 = Spack[sb * 4 + 3];
  uint32_t s25 = (uint32_t)(s0 & 0x1FFFFFFull);
  const float* Wb = W + (size_t)(sb & (NB - 1)) * 32;
  uint32_t out;
  float syd = 0.0f;
  if (t < NT) {
    uint32_t bp = bpmask[t];
    uint32_t pb = 0;
#pragma unroll
    for (int j = 0; j < NK; ++j) {
      const ull* C = Ct + (size_t)(t * NK + j) * 4;
      int par = __popcll(s0 & C[0]) + __popcll(s1 & C[1]) + __popcll(s2 & C[2]) + __popcll(s3 & C[3]);
      uint32_t bit = ((uint32_t)(par ^ (int)(bp >> j))) & 1u;
      pb |= bit << j;
      int d = (int)bit - (int)((s25 >> j) & 1u);
      syd = fmaf((float)d, Wb[j], syd);
    }
    out = pb;
  } else {
    out = s25;  // d = pb - s25 = 0
  }
  projb[e] = out;
  Syd[e] = syd;
}

// ---------------- K6: logp_x via MFMA delta-GEMM + fused softplus (log2-space) ----------
// y2 = b2 + delta (all pre-scaled by log2e). Per (t,sb):
//   sum_x softplus(s*y2) = 0.5*(Sb + Syd(t) + sum|y2|) + sum log2(1+2^-|y2|)   [in log2]
// Sb/Syd analytic; per-eval: add, add-abs, native exp2, running-product fma.
__global__ __launch_bounds__(256) void k6_mfma(const ushort* __restrict__ base2,
                                               const ushort* __restrict__ Vkpad2,
                                               const float* __restrict__ xin,
                                               const uint32_t* __restrict__ projb,
                                               const ull* __restrict__ Spack,
                                               const float* __restrict__ Syd,
                                               float* __restrict__ logpx) {
  __shared__ float bvsm[NX];  // b2 per x — 8 KB
  __shared__ float lsum[4][32];
  __shared__ float red[4];
  int sb = blockIdx.x;
  int b = sb & (NB - 1);
  int tid = threadIdx.x;
  int wave = tid >> 6, lane = tid & 63;
  int grp = lane >> 4, col = lane & 15;
  // stage base2 row (bf16 -> f32) + analytic sum_x s*b2
  const uint4* b16p = (const uint4*)(base2 + (size_t)sb * NX);
  const float4* x4p = (const float4*)(xin + (size_t)b * NX);
  float sbacc = 0.0f;
  {
    uint4 bu = b16p[tid];
    float4 xv0 = x4p[tid * 2], xv1 = x4p[tid * 2 + 1];
    uint32_t wds[4] = {bu.x, bu.y, bu.z, bu.w};
    float bv[8];
#pragma unroll
    for (int j = 0; j < 8; ++j) {
      uint32_t wd = wds[j >> 1];
      bv[j] = __uint_as_float((j & 1) ? (wd & 0xFFFF0000u) : (wd << 16));
    }
    float sg[8] = {1.0f - 2.0f * xv0.x, 1.0f - 2.0f * xv0.y, 1.0f - 2.0f * xv0.z,
                   1.0f - 2.0f * xv0.w, 1.0f - 2.0f * xv1.x, 1.0f - 2.0f * xv1.y,
                   1.0f - 2.0f * xv1.z, 1.0f - 2.0f * xv1.w};
#pragma unroll
    for (int j = 0; j < 8; ++j) {
      bvsm[tid * 8 + j] = bv[j];
      sbacc = fmaf(sg[j], bv[j], sbacc);
    }
  }
  float Sb = blockReduceSum256(sbacc, red);  // includes syncthreads (guards bvsm)
  // A-frags: lane holds m=col (t within tile), k = grp*8+j
  uint32_t s25 = (uint32_t)(Spack[sb * 4] & 0x1FFFFFFull);
  uint32_t pb0 = projb[sb * 32 + col];
  uint32_t pb1 = projb[sb * 32 + 16 + col];
  bf16x8 a0, a1;
  union { ushort u; __bf16 hh; } cvt;
#pragma unroll
  for (int j = 0; j < 8; ++j) {
    int k = grp * 8 + j;
    int sbit = (int)((s25 >> k) & 1u);
    int d0 = (int)((pb0 >> k) & 1u) - sbit;
    int d1 = (int)((pb1 >> k) & 1u) - sbit;
    cvt.u = (ushort)(d0 == 0 ? 0 : (d0 > 0 ? 0x3F80 : 0xBF80)); a0[j] = cvt.hh;
    cvt.u = (ushort)(d1 == 0 ? 0 : (d1 > 0 ? 0x3F80 : 0xBF80)); a1[j] = cvt.hh;
  }
  float acca[8], pp[8];
#pragma unroll
  for (int r = 0; r < 8; ++r) { acca[r] = 0.0f; pp[r] = 1.0f; }
  const ushort* vkbase = Vkpad2 + (size_t)(wave * 512 + col) * 32 + grp * 8;
#pragma unroll 2
  for (int i = 0; i < 32; ++i) {
    int x = (wave * 32 + i) * 16 + col;
    bf16x8 bfr = *(const bf16x8*)(vkbase + (size_t)i * 16 * 32);
    f32x4 c0 = {0.f, 0.f, 0.f, 0.f}, c1 = {0.f, 0.f, 0.f, 0.f};
    c0 = __builtin_amdgcn_mfma_f32_16x16x32_bf16(a0, bfr, c0, 0, 0, 0);
    c1 = __builtin_amdgcn_mfma_f32_16x16x32_bf16(a1, bfr, c1, 0, 0, 0);
    float bs = bvsm[x];
#pragma unroll
    for (int r = 0; r < 4; ++r) {
      float y0 = bs + c0[r];
      acca[r] += fabsf(y0);
      pp[r] = fmaf(pp[r], __builtin_amdgcn_exp2f(-fabsf(y0)), pp[r]);
      float y1 = bs + c1[r];
      acca[4 + r] += fabsf(y1);
      pp[4 + r] = fmaf(pp[4 + r], __builtin_amdgcn_exp2f(-fabsf(y1)), pp[4 + r]);
    }
  }
#pragma unroll
  for (int r = 0; r < 8; ++r) {
    float m = 0.5f * acca[r] + __log2f(pp[r]);
#pragma unroll
    for (int off = 1; off < 16; off <<= 1) m += __shfl_xor(m, off);
    if (col == 0) {
      int t = (r < 4) ? (grp * 4 + r) : (16 + grp * 4 + (r - 4));
      lsum[wave][t] = m;
    }
  }
  __syncthreads();
  if (tid < NT) {
    float tot = lsum[0][tid] + lsum[1][tid] + lsum[2][tid] + lsum[3][tid];
    tot += 0.5f * (Sb + Syd[sb * 32 + tid]);
    logpx[(size_t)tid * SBTOT + sb] = -LN2 * tot;
  }
}

// ---------------- K7: per-t weighted reduction over (s,b) ----------------
__global__ __launch_bounds__(512) void k7_reduce(const float* __restrict__ logpx,
                                                 const uint32_t* __restrict__ projb,
                                                 const float* __restrict__ qtail,
                                                 const float* __restrict__ ptail,
                                                 const float* __restrict__ baseq,
                                                 const float* __restrict__ d_lq,
                                                 const float* __restrict__ d_lpz,
                                                 const float* __restrict__ basepz,
                                                 double* __restrict__ pelbo) {
  __shared__ double red8[8];
  int t = blockIdx.x;
  int b = threadIdx.x;
  float dlq[NK];
#pragma unroll
  for (int j = 0; j < NK; ++j) dlq[j] = d_lq[b * NZ + j];
  float bq = baseq[b];
  float bpz = *basepz;
  float lq[NS], lp[NS];
#pragma unroll
  for (int s = 0; s < NS; ++s) {
    int sb = s * NB + b;
    uint32_t m = projb[sb * 32 + t];
    float sq = 0.0f, spv = 0.0f;
#pragma unroll
    for (int j = 0; j < NK; ++j) {
      float on = (float)((m >> j) & 1u);
      sq += on * dlq[j];
      spv += on * d_lpz[j];
    }
    lq[s] = bq + qtail[sb] + sq;
    lp[s] = logpx[t * SBTOT + sb] + bpz + ptail[sb] + spv;
  }
  float mx = lq[0];
#pragma unroll
  for (int s = 1; s < NS; ++s) mx = fmaxf(mx, lq[s]);
  float den = 0.0f, num = 0.0f;
#pragma unroll
  for (int s = 0; s < NS; ++s) {
    float w = __expf(lq[s] - mx);
    den += w;
    num += w * (lq[s] - lp[s]);
  }
  double v = (double)(num / den);
#pragma unroll
  for (int o = 32; o > 0; o >>= 1) v += __shfl_down(v, o);
  __syncthreads();
  if ((b & 63) == 0) red8[b >> 6] = v;
  __syncthreads();
  if (b == 0) {
    double s = 0.0;
    for (int i = 0; i < 8; ++i) s += red8[i];
    pelbo[t] = s;
  }
}

// ---------------- K8: final loss ----------------
__global__ __launch_bounds__(64) void k8_loss(const double* __restrict__ pelbo,
                                              float* __restrict__ out_loss) {
  int t = threadIdx.x;
  double v = (t < NT) ? pelbo[t] : 0.0;
#pragma unroll
  for (int o = 32; o > 0; o >>= 1) v += __shfl_down(v, o);
  if (t == 0) *out_loss = (float)(v / (double)NT);
}

extern "C" void kernel_launch(void* const* d_in, const int* in_sizes, int n_in,
                              void* d_out, int out_size, void* d_ws, size_t ws_size,
                              hipStream_t stream) {
  const float* xin = (const float*)d_in[0];
  const float* U = (const float*)d_in[1];
  const float* V = (const float*)d_in[2];
  const float* x_bias = (const float*)d_in[3];
  const float* z_bias = (const float*)d_in[4];
  float* out = (float*)d_out;

  char* p = (char*)d_ws;
  ushort* base2 = (ushort*)p;             p += (size_t)SBTOT * NX * 2;
  float* d_lq = (float*)p;                p += (size_t)NB * NZ * 4;
  float* baseq = (float*)p;               p += (size_t)NB * 4;
  float* d_lpz = (float*)p;               p += (size_t)NZ * 4;
  float* basepz = (float*)p;              p += 16;
  ull* Spack = (ull*)p;                   p += (size_t)SBTOT * 4 * 8;
  float* qtail = (float*)p;               p += (size_t)SBTOT * 4;
  float* ptail = (float*)p;               p += (size_t)SBTOT * 4;
  ull* Ct = (ull*)p;                      p += (size_t)NT * NK * 4 * 8;
  uint32_t* bpm = (uint32_t*)p;           p += 128;
  uint32_t* projb = (uint32_t*)p;         p += (size_t)SBTOT * 32 * 4;
  float* Syd = (float*)p;                 p += (size_t)SBTOT * 32 * 4;
  float* logpx = (float*)p;               p += (size_t)NT * SBTOT * 4;
  double* pelbo = (double*)p;             p += (size_t)NT * 8;
  ushort* Vkpad2 = (ushort*)p;            p += (size_t)NX * 32 * 2;
  ushort* Vbf = (ushort*)p;               p += (size_t)NX * NZ * 2;
  ushort* samp16 = (ushort*)p;            p += (size_t)SBTOT * NZ * 2;
  float* W = (float*)p;                   p += (size_t)NB * 32 * 4;
  (void)ws_size; (void)in_sizes; (void)n_in; (void)out_size;

  // JAX: key(42) -> split 4 -> kz,kx,kA,kb
  uint32_t o0[4], o1[4];
  for (int j = 0; j < 4; ++j) tf2x32(0u, 42u, (uint32_t)j, (uint32_t)(4 + j), o0[j], o1[j]);
  uint32_t kz0 = o0[0], kz1 = o0[1];
  uint32_t kx0 = o0[2], kx1 = o0[3];
  uint32_t kA0 = o1[0], kA1 = o1[1];
  uint32_t kb0 = o1[2], kb1 = o1[3];

  kP0_prep<<<NX * NZ / 256, 256, 0, stream>>>(V, z_bias, Vbf, Vkpad2, d_lpz, basepz);
  k1_q<<<NB / K1_ROWS, 256, 0, stream>>>(xin, U, z_bias, out + OFF_Q, d_lq, baseq);
  k4_rowreduce<<<NT, 256, 0, stream>>>(Ct, bpm, kA0, kA1, kb0, kb1);
  kW_signdot<<<NB, 256, 0, stream>>>(xin, Vkpad2, W);
  k2_samples<<<SBTOT, 256, 0, stream>>>(out + OFF_Q, d_lq, d_lpz, out + OFF_SAMP,
                                        samp16, Spack, qtail, ptail, kz0, kz1);
  dim3 g3(NX / 128, SBTOT / 128);
  k3m_gemm<<<g3, 256, 0, stream>>>(samp16, Vbf, x_bias, base2,
                                   out + OFF_PS, out + OFF_XO, kx0, kx1);
  k5_proj<<<SBTOT * 32 / 256, 256, 0, stream>>>(Spack, Ct, bpm, W, projb, Syd);
  k6_mfma<<<SBTOT, 256, 0, stream>>>(base2, Vkpad2, xin, projb, Spack, Syd, logpx);
  k7_reduce<<<NT, 512, 0, stream>>>(logpx, projb, qtail, ptail, baseq, d_lq,
                                    d_lpz, basepz, pelbo);
  k8_loss<<<1, 64, 0, stream>>>(pelbo, out + OFF_LOSS);
}

// Round 5
// 325.536 us; speedup vs baseline: 3.9732x; 1.1176x over previous
//
#include <hip/hip_runtime.h>
#include <cstdint>

// Problem constants (setup_inputs fixed: nx=2048, nz=256, B=512, S=10, k=25, T=30)
#define NX 2048
#define NZ 256
#define NB 512
#define NS 10
#define NK 25
#define NT 30
#define SBTOT (NS * NB)  // 5120

#define LOG2E 1.4426950408889634f
#define LN2 0.6931471805599453f

// d_out flat layout (all float32): q, samples_z, ps, xouts, loss
#define OFF_Q 0
#define OFF_SAMP (NB * NZ)
#define OFF_PS (OFF_SAMP + SBTOT * NZ)
#define OFF_XO (OFF_PS + SBTOT * NX)
#define OFF_LOSS (OFF_XO + SBTOT * NX)

typedef unsigned long long ull;
typedef __bf16 bf16x8 __attribute__((ext_vector_type(8)));
typedef float f32x4 __attribute__((ext_vector_type(4)));

// ---------------- JAX Threefry-2x32 (exact) ----------------
__host__ __device__ inline void tf2x32(uint32_t k0, uint32_t k1, uint32_t x0, uint32_t x1,
                                       uint32_t& o0, uint32_t& o1) {
  uint32_t k2 = k0 ^ k1 ^ 0x1BD11BDAu;
  x0 += k0; x1 += k1;
#define TF_R(r) { x0 += x1; x1 = (x1 << (r)) | (x1 >> (32 - (r))); x1 ^= x0; }
  TF_R(13) TF_R(15) TF_R(26) TF_R(6)
  x0 += k1; x1 += k2 + 1u;
  TF_R(17) TF_R(29) TF_R(16) TF_R(24)
  x0 += k2; x1 += k0 + 2u;
  TF_R(13) TF_R(15) TF_R(26) TF_R(6)
  x0 += k0; x1 += k1 + 3u;
  TF_R(17) TF_R(29) TF_R(16) TF_R(24)
  x0 += k1; x1 += k2 + 4u;
  TF_R(13) TF_R(15) TF_R(26) TF_R(6)
  x0 += k2; x1 += k0 + 5u;
#undef TF_R
  o0 = x0; o1 = x1;
}

// JAX threefry over iota(n): element i (h=n/2): i<h -> o0(i,i+h); else o1(i-h,i)
__device__ inline uint32_t tf_select(uint32_t k0, uint32_t k1, uint32_t i, uint32_t h) {
  bool lo = i < h;
  uint32_t x0 = lo ? i : i - h;
  uint32_t x1 = lo ? i + h : i;
  uint32_t o0, o1;
  tf2x32(k0, k1, x0, x1, o0, o1);
  return lo ? o0 : o1;
}

__device__ inline float tf_uniform(uint32_t k0, uint32_t k1, uint32_t i, uint32_t h) {
  uint32_t r = tf_select(k0, k1, i, h);
  return __uint_as_float(0x3f800000u | (r >> 9)) - 1.0f;  // [0,1), exactly JAX
}

__device__ inline float sigclip(float a) {
  float p = 1.0f / (1.0f + __expf(-a));
  return fminf(fmaxf(p, 1e-6f), 1.0f - 1e-6f);
}

__device__ inline ushort f2bf(float f) {  // RNE f32->bf16 (no NaN inputs here)
  uint32_t u = __float_as_uint(f);
  return (ushort)((u + 0x7FFFu + ((u >> 16) & 1u)) >> 16);
}

__device__ inline float blockReduceSum256(float v, volatile float* s4) {
#pragma unroll
  for (int o = 32; o > 0; o >>= 1) v += __shfl_down(v, o);
  __syncthreads();
  if ((threadIdx.x & 63) == 0) s4[threadIdx.x >> 6] = v;
  __syncthreads();
  return s4[0] + s4[1] + s4[2] + s4[3];
}

// ---------------- KP0: Vbf (bf16 V), Vkpad2 (bf16 V[:, :25]*log2e padded), pz terms ----
__global__ __launch_bounds__(256) void kP0_prep(const float* __restrict__ V,
                                                const float* __restrict__ z_bias,
                                                ushort* __restrict__ Vbf,
                                                ushort* __restrict__ Vkpad2,
                                                float* __restrict__ d_lpz,
                                                float* __restrict__ basepz) {
  __shared__ float red[4];
  int e = blockIdx.x * 256 + threadIdx.x;  // < NX*NZ
  int x = e >> 8, k = e & 255;
  float v = V[e];
  Vbf[e] = f2bf(v);
  if (k < 32) Vkpad2[x * 32 + k] = (k < NK) ? f2bf(v * LOG2E) : (ushort)0;
  if (blockIdx.x == 0) {
    int z = threadIdx.x;
    float pz = sigclip(z_bias[z]);
    float lp = __logf(pz), l1 = __logf(1.0f - pz);
    d_lpz[z] = lp - l1;
    float s = blockReduceSum256(l1, red);
    if (z == 0) *basepz = s;
  }
}

// ---------------- KW: W[b][k] = sum_x (1-2*xin[b,x]) * bf16val(Vkpad2[x,k]) ----------
__global__ __launch_bounds__(256) void kW_signdot(const float* __restrict__ xin,
                                                  const ushort* __restrict__ Vkpad2,
                                                  float* __restrict__ W) {
  __shared__ float wred[4][NK];
  int b = blockIdx.x;
  int tid = threadIdx.x;
  float acc[NK];
#pragma unroll
  for (int j = 0; j < NK; ++j) acc[j] = 0.0f;
#pragma unroll
  for (int i = 0; i < 8; ++i) {
    int x = i * 256 + tid;
    float s = 1.0f - 2.0f * xin[(size_t)b * NX + x];
    const uint4* vp = (const uint4*)(Vkpad2 + (size_t)x * 32);
    uint4 q0 = vp[0], q1 = vp[1], q2 = vp[2], q3 = vp[3];
    uint32_t w[16] = {q0.x, q0.y, q0.z, q0.w, q1.x, q1.y, q1.z, q1.w,
                      q2.x, q2.y, q2.z, q2.w, q3.x, q3.y, q3.z, q3.w};
#pragma unroll
    for (int j = 0; j < NK; ++j) {
      uint32_t wd = w[j >> 1];
      float v = __uint_as_float((j & 1) ? (wd & 0xFFFF0000u) : (wd << 16));
      acc[j] = fmaf(s, v, acc[j]);
    }
  }
#pragma unroll
  for (int j = 0; j < NK; ++j) {
#pragma unroll
    for (int o = 1; o < 64; o <<= 1) acc[j] += __shfl_xor(acc[j], o);
  }
  if ((tid & 63) == 0) {
#pragma unroll
    for (int j = 0; j < NK; ++j) wred[tid >> 6][j] = acc[j];
  }
  __syncthreads();
  if (tid < NK) W[b * 32 + tid] = wred[0][tid] + wred[1][tid] + wred[2][tid] + wred[3][tid];
}

// ---------------- K1: q = clip(sigmoid(xin @ U^T + z_bias)) ----------------
#define K1_ROWS 4
__global__ __launch_bounds__(256) void k1_q(const float* __restrict__ xin,
                                            const float* __restrict__ U,
                                            const float* __restrict__ z_bias,
                                            float* __restrict__ outq,
                                            float* __restrict__ d_lq,
                                            float* __restrict__ baseq) {
  __shared__ float xs[K1_ROWS][NX];
  __shared__ float red[4];
  int b0 = blockIdx.x * K1_ROWS;
  int tid = threadIdx.x;
  const float4* src = (const float4*)(xin + (size_t)b0 * NX);
  float4* dst = (float4*)(&xs[0][0]);
  for (int i = tid; i < K1_ROWS * NX / 4; i += 256) dst[i] = src[i];
  __syncthreads();
  int z = tid;
  float acc[K1_ROWS];
#pragma unroll
  for (int r = 0; r < K1_ROWS; ++r) acc[r] = 0.0f;
  const float4* U4 = (const float4*)(U + (size_t)z * NX);
  for (int i4 = 0; i4 < NX / 4; ++i4) {
    float4 u = U4[i4];
    int i = i4 * 4;
#pragma unroll
    for (int r = 0; r < K1_ROWS; ++r)
      acc[r] += u.x * xs[r][i] + u.y * xs[r][i + 1] + u.z * xs[r][i + 2] + u.w * xs[r][i + 3];
  }
  float zb = z_bias[z];
  for (int r = 0; r < K1_ROWS; ++r) {
    int b = b0 + r;
    float q = sigclip(acc[r] + zb);
    outq[b * NZ + z] = q;
    float lq = __logf(q), l1 = __logf(1.0f - q);
    d_lq[b * NZ + z] = lq - l1;
    float s = blockReduceSum256(l1, red);
    if (tid == 0) baseq[b] = s;
  }
}

// ---------------- K2: samples_z (f32 + bf16) + packed bits + tails ----------------
__global__ __launch_bounds__(256) void k2_samples(const float* __restrict__ q,
                                                  const float* __restrict__ d_lq,
                                                  const float* __restrict__ d_lpz,
                                                  float* __restrict__ samp_out,
                                                  ushort* __restrict__ samp16,
                                                  ull* __restrict__ Spack,
                                                  float* __restrict__ qtail,
                                                  float* __restrict__ ptail,
                                                  uint32_t kz0, uint32_t kz1) {
  __shared__ float red[4];
  int sb = blockIdx.x;
  int z = threadIdx.x;
  int b = sb & (NB - 1);
  uint32_t i = (uint32_t)sb * NZ + z;
  const uint32_t h = (uint32_t)SBTOT * NZ / 2;
  float u = tf_uniform(kz0, kz1, i, h);
  float qv = q[b * NZ + z];
  int smp = (u < qv) ? 1 : 0;
  samp_out[i] = (float)smp;
  samp16[i] = smp ? (ushort)0x3F80 : (ushort)0;
  ull m = __ballot(smp);
  if ((z & 63) == 0) Spack[sb * 4 + (z >> 6)] = m;
  float dq = (z >= NK && smp) ? d_lq[b * NZ + z] : 0.0f;
  float dp = (z >= NK && smp) ? d_lpz[z] : 0.0f;
  float sq = blockReduceSum256(dq, red);
  float sp = blockReduceSum256(dp, red);
  if (z == 0) { qtail[sb] = sq; ptail[sb] = sp; }
}

// ---------------- K3M: bf16 MFMA GEMM (operand-swapped): C[x][sb] = V·samp^T ------
// Tile: 128 x-rows × 64 sb-cols, 4 waves (wave owns 32 x-rows). Lane holds 4
// consecutive x per acc reg-group -> dwordx4 ps/xo stores, dwordx2 bf16 base2.
__global__ __launch_bounds__(256) void k3m_gemm(const ushort* __restrict__ samp16,
                                                const ushort* __restrict__ Vbf,
                                                const float* __restrict__ x_bias,
                                                ushort* __restrict__ base2,
                                                float* __restrict__ ps_out,
                                                float* __restrict__ xo_out,
                                                uint32_t kx0, uint32_t kx1) {
  __shared__ __align__(16) ushort As[128 * 32];  // V rows (x)     8 KB
  __shared__ __align__(16) ushort Bs[64 * 32];   // samp rows (sb) 4 KB
  int tid = threadIdx.x;
  int wave = tid >> 6, lane = tid & 63, grp = lane >> 4, col = lane & 15;
  int x0 = blockIdx.x * 128, sb0 = blockIdx.y * 64;
  f32x4 acc[2][4];
#pragma unroll
  for (int mi = 0; mi < 2; ++mi)
#pragma unroll
    for (int ni = 0; ni < 4; ++ni) acc[mi][ni] = (f32x4){0.f, 0.f, 0.f, 0.f};

  for (int k0 = 0; k0 < NZ; k0 += 32) {
    {
      int rowb = tid >> 2, kcb = (tid & 3) << 3;
      *(uint4*)&Bs[rowb * 32 + kcb] = *(const uint4*)&samp16[(size_t)(sb0 + rowb) * NZ + k0 + kcb];
#pragma unroll
      for (int c = tid; c < 512; c += 256) {
        int rowa = c >> 2, kca = (c & 3) << 3;
        *(uint4*)&As[rowa * 32 + kca] = *(const uint4*)&Vbf[(size_t)(x0 + rowa) * NZ + k0 + kca];
      }
    }
    __syncthreads();
    bf16x8 af[2], bfv[4];
#pragma unroll
    for (int mi = 0; mi < 2; ++mi)
      af[mi] = *(const bf16x8*)&As[(wave * 32 + mi * 16 + col) * 32 + grp * 8];
#pragma unroll
    for (int ni = 0; ni < 4; ++ni)
      bfv[ni] = *(const bf16x8*)&Bs[(ni * 16 + col) * 32 + grp * 8];
#pragma unroll
    for (int mi = 0; mi < 2; ++mi)
#pragma unroll
      for (int ni = 0; ni < 4; ++ni)
        acc[mi][ni] = __builtin_amdgcn_mfma_f32_16x16x32_bf16(af[mi], bfv[ni], acc[mi][ni], 0, 0, 0);
    __syncthreads();
  }
  const uint32_t h = (uint32_t)SBTOT * NX / 2;
#pragma unroll
  for (int mi = 0; mi < 2; ++mi) {
    int xb = x0 + wave * 32 + mi * 16 + grp * 4;  // 4 consecutive x per lane
    float4 xb4 = *(const float4*)(x_bias + xb);
#pragma unroll
    for (int ni = 0; ni < 4; ++ni) {
      int sb = sb0 + ni * 16 + col;
      size_t off = (size_t)sb * NX + xb;
      float a0 = acc[mi][ni][0] + xb4.x;
      float a1 = acc[mi][ni][1] + xb4.y;
      float a2 = acc[mi][ni][2] + xb4.z;
      float a3 = acc[mi][ni][3] + xb4.w;
      uint2 bp;
      bp.x = (uint32_t)f2bf(a0 * LOG2E) | ((uint32_t)f2bf(a1 * LOG2E) << 16);
      bp.y = (uint32_t)f2bf(a2 * LOG2E) | ((uint32_t)f2bf(a3 * LOG2E) << 16);
      *(uint2*)(base2 + off) = bp;
      float4 pv = make_float4(sigclip(a0), sigclip(a1), sigclip(a2), sigclip(a3));
      *(float4*)(ps_out + off) = pv;
      uint32_t fi = (uint32_t)sb * NX + xb;
      float4 xv;
      xv.x = (tf_uniform(kx0, kx1, fi + 0, h) < pv.x) ? 1.0f : 0.0f;
      xv.y = (tf_uniform(kx0, kx1, fi + 1, h) < pv.y) ? 1.0f : 0.0f;
      xv.z = (tf_uniform(kx0, kx1, fi + 2, h) < pv.z) ? 1.0f : 0.0f;
      xv.w = (tf_uniform(kx0, kx1, fi + 3, h) < pv.w) ? 1.0f : 0.0f;
      *(float4*)(xo_out + off) = xv;
    }
  }
}

// ---------------- K4: GF(2) row reduce (parallel bit-gen + wave0 elimination) ----------------
__global__ __launch_bounds__(256) void k4_rowreduce(ull* __restrict__ Ct,
                                                    uint32_t* __restrict__ bpmask,
                                                    uint32_t kA0, uint32_t kA1,
                                                    uint32_t kb0, uint32_t kb1) {
  __shared__ uint32_t Aw[NK][8];
  __shared__ uint32_t bbsh[NK];
  int t = blockIdx.x;
  int tid = threadIdx.x;
  if (tid < NK * 8) {
    int r = tid >> 3, c = tid & 7;
    const uint32_t hA = (uint32_t)NT * NK * NZ / 2;
    uint32_t base_i = (uint32_t)(t * NK + r) * NZ + c * 32;
    uint32_t w = 0;
    for (int zz = 0; zz < 32; ++zz) {
      uint32_t rr = tf_select(kA0, kA1, base_i + zz, hA);
      w |= ((rr >> 31) ^ 1u) << zz;  // bit=1 iff u<0.5 (top bit 0)
    }
    Aw[r][c] = w;
  }
  if (tid < NK) {
    const uint32_t hb = (uint32_t)NT * NK / 2;
    uint32_t rb = tf_select(kb0, kb1, (uint32_t)(t * NK + tid), hb);
    bbsh[tid] = (rb >> 31) ^ 1u;
  }
  __syncthreads();
  if (tid >= 64) return;  // wave 0 does the elimination
  int lane = tid;
  ull w0 = 0, w1 = 0, w2 = 0, w3 = 0;
  uint32_t bbit = 0;
  if (lane < NK) {
    w0 = (ull)Aw[lane][0] | ((ull)Aw[lane][1] << 32);
    w1 = (ull)Aw[lane][2] | ((ull)Aw[lane][3] << 32);
    w2 = (ull)Aw[lane][4] | ((ull)Aw[lane][5] << 32);
    w3 = (ull)Aw[lane][6] | ((ull)Aw[lane][7] << 32);
    bbit = bbsh[lane];
  }
  for (int i = 0; i < NK; ++i) {
    int mybit = (int)((w0 >> i) & 1ull);
    ull mask = __ballot(lane < NK && mybit);
    ull cand = mask & (~0ull << i);
    int p = cand ? __builtin_ctzll(cand) : (NK - 1);
    int srcl = (lane == i) ? p : ((lane == p) ? i : lane);
    w0 = __shfl(w0, srcl); w1 = __shfl(w1, srcl); w2 = __shfl(w2, srcl); w3 = __shfl(w3, srcl);
    bbit = __shfl(bbit, srcl);
    ull p0 = __shfl(w0, i), p1 = __shfl(w1, i), p2 = __shfl(w2, i), p3 = __shfl(w3, i);
    uint32_t pvb = __shfl(bbit, i);
    int nb2 = (int)((w0 >> i) & 1ull);
    if (lane < NK && lane != i && nb2) {
      w0 ^= p0; w1 ^= p1; w2 ^= p2; w3 ^= p3; bbit ^= pvb;
    }
  }
  if (lane < NK) {
    w0 &= ~((1ull << NK) - 1ull);  // only columns z>=k feed proj
    ull* dstp = Ct + (size_t)(t * NK + lane) * 4;
    dstp[0] = w0; dstp[1] = w1; dstp[2] = w2; dstp[3] = w3;
  }
  ull bm = __ballot(lane < NK && bbit);
  if (lane == 0) bpmask[t] = (uint32_t)bm & 0x1FFFFFFu;
}

// ---------------- K5: proj bits + Syd = sum_j d_j*W[b,j]; layout [sb*32+t] -------
__global__ __launch_bounds__(256) void k5_proj(const ull* __restrict__ Spack,
                                               const ull* __restrict__ Ct,
                                               const uint32_t* __restrict__ bpmask,
                                               const float* __restrict__ W,
                                               uint32_t* __restrict__ projb,
                                               float* __restrict__ Syd) {
  int e = blockIdx.x * 256 + threadIdx.x;  // < SBTOT*32
  int sb = e >> 5, t = e & 31;
  ull s0 = Spack[sb * 4 + 0], s1 = Spack[sb * 4 + 1];
  ull s2 = Spack[sb * 4 + 2], s3 = Spack[sb * 4 + 3];
  uint32_t s25 = (uint32_t)(s0 & 0x1FFFFFFull);
  const float* Wb = W + (size_t)(sb & (NB - 1)) * 32;
  uint32_t out;
  float syd = 0.0f;
  if (t < NT) {
    uint32_t bp = bpmask[t];
    uint32_t pb = 0;
#pragma unroll
    for (int j = 0; j < NK; ++j) {
      const ull* C = Ct + (size_t)(t * NK + j) * 4;
      int par = __popcll(s0 & C[0]) + __popcll(s1 & C[1]) + __popcll(s2 & C[2]) + __popcll(s3 & C[3]);
      uint32_t bit = ((uint32_t)(par ^ (int)(bp >> j))) & 1u;
      pb |= bit << j;
      int d = (int)bit - (int)((s25 >> j) & 1u);
      syd = fmaf((float)d, Wb[j], syd);
    }
    out = pb;
  } else {
    out = s25;  // d = pb - s25 = 0
  }
  projb[e] = out;
  Syd[e] = syd;
}

// ---------------- K6: logp_x via MFMA delta-GEMM + fused softplus (log2-space) ----------
__global__ __launch_bounds__(256) void k6_mfma(const ushort* __restrict__ base2,
                                               const ushort* __restrict__ Vkpad2,
                                               const float* __restrict__ xin,
                                               const uint32_t* __restrict__ projb,
                                               const ull* __restrict__ Spack,
                                               const float* __restrict__ Syd,
                                               float* __restrict__ logpx) {
  __shared__ float bvsm[NX];  // b2 per x — 8 KB
  __shared__ float lsum[4][32];
  __shared__ float red[4];
  int sb = blockIdx.x;
  int b = sb & (NB - 1);
  int tid = threadIdx.x;
  int wave = tid >> 6, lane = tid & 63;
  int grp = lane >> 4, col = lane & 15;
  // stage base2 row (bf16 -> f32) + analytic sum_x s*b2
  const uint4* b16p = (const uint4*)(base2 + (size_t)sb * NX);
  const float4* x4p = (const float4*)(xin + (size_t)b * NX);
  float sbacc = 0.0f;
  {
    uint4 bu = b16p[tid];
    float4 xv0 = x4p[tid * 2], xv1 = x4p[tid * 2 + 1];
    uint32_t wds[4] = {bu.x, bu.y, bu.z, bu.w};
    float bv[8];
#pragma unroll
    for (int j = 0; j < 8; ++j) {
      uint32_t wd = wds[j >> 1];
      bv[j] = __uint_as_float((j & 1) ? (wd & 0xFFFF0000u) : (wd << 16));
    }
    float sg[8] = {1.0f - 2.0f * xv0.x, 1.0f - 2.0f * xv0.y, 1.0f - 2.0f * xv0.z,
                   1.0f - 2.0f * xv0.w, 1.0f - 2.0f * xv1.x, 1.0f - 2.0f * xv1.y,
                   1.0f - 2.0f * xv1.z, 1.0f - 2.0f * xv1.w};
#pragma unroll
    for (int j = 0; j < 8; ++j) {
      bvsm[tid * 8 + j] = bv[j];
      sbacc = fmaf(sg[j], bv[j], sbacc);
    }
  }
  float Sb = blockReduceSum256(sbacc, red);  // includes syncthreads (guards bvsm)
  // A-frags: lane holds m=col (t within tile), k = grp*8+j
  uint32_t s25 = (uint32_t)(Spack[sb * 4] & 0x1FFFFFFull);
  uint32_t pb0 = projb[sb * 32 + col];
  uint32_t pb1 = projb[sb * 32 + 16 + col];
  bf16x8 a0, a1;
  union { ushort u; __bf16 hh; } cvt;
#pragma unroll
  for (int j = 0; j < 8; ++j) {
    int k = grp * 8 + j;
    int sbit = (int)((s25 >> k) & 1u);
    int d0 = (int)((pb0 >> k) & 1u) - sbit;
    int d1 = (int)((pb1 >> k) & 1u) - sbit;
    cvt.u = (ushort)(d0 == 0 ? 0 : (d0 > 0 ? 0x3F80 : 0xBF80)); a0[j] = cvt.hh;
    cvt.u = (ushort)(d1 == 0 ? 0 : (d1 > 0 ? 0x3F80 : 0xBF80)); a1[j] = cvt.hh;
  }
  float acca[8], pp[8];
#pragma unroll
  for (int r = 0; r < 8; ++r) { acca[r] = 0.0f; pp[r] = 1.0f; }
  const ushort* vkbase = Vkpad2 + (size_t)(wave * 512 + col) * 32 + grp * 8;
#pragma unroll 2
  for (int i = 0; i < 32; ++i) {
    int x = (wave * 32 + i) * 16 + col;
    bf16x8 bfr = *(const bf16x8*)(vkbase + (size_t)i * 16 * 32);
    f32x4 c0 = {0.f, 0.f, 0.f, 0.f}, c1 = {0.f, 0.f, 0.f, 0.f};
    c0 = __builtin_amdgcn_mfma_f32_16x16x32_bf16(a0, bfr, c0, 0, 0, 0);
    c1 = __builtin_amdgcn_mfma_f32_16x16x32_bf16(a1, bfr, c1, 0, 0, 0);
    float bs = bvsm[x];
#pragma unroll
    for (int r = 0; r < 4; ++r) {
      float y0 = bs + c0[r];
      acca[r] += fabsf(y0);
      pp[r] = fmaf(pp[r], __builtin_amdgcn_exp2f(-fabsf(y0)), pp[r]);
      float y1 = bs + c1[r];
      acca[4 + r] += fabsf(y1);
      pp[4 + r] = fmaf(pp[4 + r], __builtin_amdgcn_exp2f(-fabsf(y1)), pp[4 + r]);
    }
  }
#pragma unroll
  for (int r = 0; r < 8; ++r) {
    float m = 0.5f * acca[r] + __log2f(pp[r]);
#pragma unroll
    for (int off = 1; off < 16; off <<= 1) m += __shfl_xor(m, off);
    if (col == 0) {
      int t = (r < 4) ? (grp * 4 + r) : (16 + grp * 4 + (r - 4));
      lsum[wave][t] = m;
    }
  }
  __syncthreads();
  if (tid < NT) {
    float tot = lsum[0][tid] + lsum[1][tid] + lsum[2][tid] + lsum[3][tid];
    tot += 0.5f * (Sb + Syd[sb * 32 + tid]);
    logpx[(size_t)tid * SBTOT + sb] = -LN2 * tot;
  }
}

// ---------------- K7: per-t weighted reduction over (s,b) ----------------
__global__ __launch_bounds__(512) void k7_reduce(const float* __restrict__ logpx,
                                                 const uint32_t* __restrict__ projb,
                                                 const float* __restrict__ qtail,
                                                 const float* __restrict__ ptail,
                                                 const float* __restrict__ baseq,
                                                 const float* __restrict__ d_lq,
                                                 const float* __restrict__ d_lpz,
                                                 const float* __restrict__ basepz,
                                                 double* __restrict__ pelbo) {
  __shared__ double red8[8];
  int t = blockIdx.x;
  int b = threadIdx.x;
  float dlq[NK];
#pragma unroll
  for (int j = 0; j < NK; ++j) dlq[j] = d_lq[b * NZ + j];
  float bq = baseq[b];
  float bpz = *basepz;
  float lq[NS], lp[NS];
#pragma unroll
  for (int s = 0; s < NS; ++s) {
    int sb = s * NB + b;
    uint32_t m = projb[sb * 32 + t];
    float sq = 0.0f, spv = 0.0f;
#pragma unroll
    for (int j = 0; j < NK; ++j) {
      float on = (float)((m >> j) & 1u);
      sq += on * dlq[j];
      spv += on * d_lpz[j];
    }
    lq[s] = bq + qtail[sb] + sq;
    lp[s] = logpx[t * SBTOT + sb] + bpz + ptail[sb] + spv;
  }
  float mx = lq[0];
#pragma unroll
  for (int s = 1; s < NS; ++s) mx = fmaxf(mx, lq[s]);
  float den = 0.0f, num = 0.0f;
#pragma unroll
  for (int s = 0; s < NS; ++s) {
    float w = __expf(lq[s] - mx);
    den += w;
    num += w * (lq[s] - lp[s]);
  }
  double v = (double)(num / den);
#pragma unroll
  for (int o = 32; o > 0; o >>= 1) v += __shfl_down(v, o);
  __syncthreads();
  if ((b & 63) == 0) red8[b >> 6] = v;
  __syncthreads();
  if (b == 0) {
    double s = 0.0;
    for (int i = 0; i < 8; ++i) s += red8[i];
    pelbo[t] = s;
  }
}

// ---------------- K8: final loss ----------------
__global__ __launch_bounds__(64) void k8_loss(const double* __restrict__ pelbo,
                                              float* __restrict__ out_loss) {
  int t = threadIdx.x;
  double v = (t < NT) ? pelbo[t] : 0.0;
#pragma unroll
  for (int o = 32; o > 0; o >>= 1) v += __shfl_down(v, o);
  if (t == 0) *out_loss = (float)(v / (double)NT);
}

extern "C" void kernel_launch(void* const* d_in, const int* in_sizes, int n_in,
                              void* d_out, int out_size, void* d_ws, size_t ws_size,
                              hipStream_t stream) {
  const float* xin = (const float*)d_in[0];
  const float* U = (const float*)d_in[1];
  const float* V = (const float*)d_in[2];
  const float* x_bias = (const float*)d_in[3];
  const float* z_bias = (const float*)d_in[4];
  float* out = (float*)d_out;

  char* p = (char*)d_ws;
  ushort* base2 = (ushort*)p;             p += (size_t)SBTOT * NX * 2;
  float* d_lq = (float*)p;                p += (size_t)NB * NZ * 4;
  float* baseq = (float*)p;               p += (size_t)NB * 4;
  float* d_lpz = (float*)p;               p += (size_t)NZ * 4;
  float* basepz = (float*)p;              p += 16;
  ull* Spack = (ull*)p;                   p += (size_t)SBTOT * 4 * 8;
  float* qtail = (float*)p;               p += (size_t)SBTOT * 4;
  float* ptail = (float*)p;               p += (size_t)SBTOT * 4;
  ull* Ct = (ull*)p;                      p += (size_t)NT * NK * 4 * 8;
  uint32_t* bpm = (uint32_t*)p;           p += 128;
  uint32_t* projb = (uint32_t*)p;         p += (size_t)SBTOT * 32 * 4;
  float* Syd = (float*)p;                 p += (size_t)SBTOT * 32 * 4;
  float* logpx = (float*)p;               p += (size_t)NT * SBTOT * 4;
  double* pelbo = (double*)p;             p += (size_t)NT * 8;
  ushort* Vkpad2 = (ushort*)p;            p += (size_t)NX * 32 * 2;
  ushort* Vbf = (ushort*)p;               p += (size_t)NX * NZ * 2;
  ushort* samp16 = (ushort*)p;            p += (size_t)SBTOT * NZ * 2;
  float* W = (float*)p;                   p += (size_t)NB * 32 * 4;
  (void)ws_size; (void)in_sizes; (void)n_in; (void)out_size;

  // JAX: key(42) -> split 4 -> kz,kx,kA,kb
  uint32_t o0[4], o1[4];
  for (int j = 0; j < 4; ++j) tf2x32(0u, 42u, (uint32_t)j, (uint32_t)(4 + j), o0[j], o1[j]);
  uint32_t kz0 = o0[0], kz1 = o0[1];
  uint32_t kx0 = o0[2], kx1 = o0[3];
  uint32_t kA0 = o1[0], kA1 = o1[1];
  uint32_t kb0 = o1[2], kb1 = o1[3];

  kP0_prep<<<NX * NZ / 256, 256, 0, stream>>>(V, z_bias, Vbf, Vkpad2, d_lpz, basepz);
  k1_q<<<NB / K1_ROWS, 256, 0, stream>>>(xin, U, z_bias, out + OFF_Q, d_lq, baseq);
  k4_rowreduce<<<NT, 256, 0, stream>>>(Ct, bpm, kA0, kA1, kb0, kb1);
  kW_signdot<<<NB, 256, 0, stream>>>(xin, Vkpad2, W);
  k2_samples<<<SBTOT, 256, 0, stream>>>(out + OFF_Q, d_lq, d_lpz, out + OFF_SAMP,
                                        samp16, Spack, qtail, ptail, kz0, kz1);
  dim3 g3(NX / 128, SBTOT / 64);
  k3m_gemm<<<g3, 256, 0, stream>>>(samp16, Vbf, x_bias, base2,
                                   out + OFF_PS, out + OFF_XO, kx0, kx1);
  k5_proj<<<SBTOT * 32 / 256, 256, 0, stream>>>(Spack, Ct, bpm, W, projb, Syd);
  k6_mfma<<<SBTOT, 256, 0, stream>>>(base2, Vkpad2, xin, projb, Spack, Syd, logpx);
  k7_reduce<<<NT, 512, 0, stream>>>(logpx, projb, qtail, ptail, baseq, d_lq,
                                    d_lpz, basepz, pelbo);
  k8_loss<<<1, 64, 0, stream>>>(pelbo, out + OFF_LOSS);
}

// Round 6
// 274.091 us; speedup vs baseline: 4.7189x; 1.1877x over previous
//
#include <hip/hip_runtime.h>
#include <cstdint>

// Problem constants (setup_inputs fixed: nx=2048, nz=256, B=512, S=10, k=25, T=30)
#define NX 2048
#define NZ 256
#define NB 512
#define NS 10
#define NK 25
#define NT 30
#define SBTOT (NS * NB)  // 5120

#define LOG2E 1.4426950408889634f
#define LN2 0.6931471805599453f

// d_out flat layout (all float32): q, samples_z, ps, xouts, loss
#define OFF_Q 0
#define OFF_SAMP (NB * NZ)
#define OFF_PS (OFF_SAMP + SBTOT * NZ)
#define OFF_XO (OFF_PS + SBTOT * NX)
#define OFF_LOSS (OFF_XO + SBTOT * NX)

typedef unsigned long long ull;
typedef __bf16 bf16x8 __attribute__((ext_vector_type(8)));
typedef float f32x4 __attribute__((ext_vector_type(4)));

// ---------------- JAX Threefry-2x32 (exact) ----------------
__host__ __device__ inline void tf2x32(uint32_t k0, uint32_t k1, uint32_t x0, uint32_t x1,
                                       uint32_t& o0, uint32_t& o1) {
  uint32_t k2 = k0 ^ k1 ^ 0x1BD11BDAu;
  x0 += k0; x1 += k1;
#define TF_R(r) { x0 += x1; x1 = (x1 << (r)) | (x1 >> (32 - (r))); x1 ^= x0; }
  TF_R(13) TF_R(15) TF_R(26) TF_R(6)
  x0 += k1; x1 += k2 + 1u;
  TF_R(17) TF_R(29) TF_R(16) TF_R(24)
  x0 += k2; x1 += k0 + 2u;
  TF_R(13) TF_R(15) TF_R(26) TF_R(6)
  x0 += k0; x1 += k1 + 3u;
  TF_R(17) TF_R(29) TF_R(16) TF_R(24)
  x0 += k1; x1 += k2 + 4u;
  TF_R(13) TF_R(15) TF_R(26) TF_R(6)
  x0 += k2; x1 += k0 + 5u;
#undef TF_R
  o0 = x0; o1 = x1;
}

// JAX threefry over iota(n): element i (h=n/2): i<h -> o0(i,i+h); else o1(i-h,i)
__device__ inline uint32_t tf_select(uint32_t k0, uint32_t k1, uint32_t i, uint32_t h) {
  bool lo = i < h;
  uint32_t x0 = lo ? i : i - h;
  uint32_t x1 = lo ? i + h : i;
  uint32_t o0, o1;
  tf2x32(k0, k1, x0, x1, o0, o1);
  return lo ? o0 : o1;
}

__device__ inline float tf_uniform(uint32_t k0, uint32_t k1, uint32_t i, uint32_t h) {
  uint32_t r = tf_select(k0, k1, i, h);
  return __uint_as_float(0x3f800000u | (r >> 9)) - 1.0f;  // [0,1), exactly JAX
}

__device__ inline float sigclip(float a) {
  float p = 1.0f / (1.0f + __expf(-a));
  return fminf(fmaxf(p, 1e-6f), 1.0f - 1e-6f);
}

__device__ inline ushort f2bf(float f) {  // RNE f32->bf16 (no NaN inputs here)
  uint32_t u = __float_as_uint(f);
  return (ushort)((u + 0x7FFFu + ((u >> 16) & 1u)) >> 16);
}

__device__ inline float blockReduceSum256(float v, volatile float* s4) {
#pragma unroll
  for (int o = 32; o > 0; o >>= 1) v += __shfl_down(v, o);
  __syncthreads();
  if ((threadIdx.x & 63) == 0) s4[threadIdx.x >> 6] = v;
  __syncthreads();
  return s4[0] + s4[1] + s4[2] + s4[3];
}

// ---------------- KP0: Vbf, Vkpad2, Uhi/Ulo split, xinbf, zero baseq, pz terms ----
__global__ __launch_bounds__(256) void kP0_prep(const float* __restrict__ V,
                                                const float* __restrict__ U,
                                                const float* __restrict__ xin,
                                                const float* __restrict__ z_bias,
                                                ushort* __restrict__ Vbf,
                                                ushort* __restrict__ Vkpad2,
                                                ushort* __restrict__ Uhi,
                                                ushort* __restrict__ Ulo,
                                                ushort* __restrict__ xinbf,
                                                float* __restrict__ baseq,
                                                float* __restrict__ d_lpz,
                                                float* __restrict__ basepz) {
  __shared__ float red[4];
  int e = blockIdx.x * 256 + threadIdx.x;  // < NX*NZ = 524288
  {  // V
    int x = e >> 8, k = e & 255;
    float v = V[e];
    Vbf[e] = f2bf(v);
    if (k < 32) Vkpad2[x * 32 + k] = (k < NK) ? f2bf(v * LOG2E) : (ushort)0;
  }
  {  // U split hi/lo (U is [NZ][NX], 524288 elements)
    float u = U[e];
    ushort hi = f2bf(u);
    Uhi[e] = hi;
    float hv = __uint_as_float((uint32_t)hi << 16);
    Ulo[e] = f2bf(u - hv);
  }
  {  // xin cast (1048576 elements, 2 per thread)
    xinbf[e] = (xin[e] > 0.5f) ? (ushort)0x3F80 : (ushort)0;
    int e2 = e + NX * NZ;
    xinbf[e2] = (xin[e2] > 0.5f) ? (ushort)0x3F80 : (ushort)0;
  }
  if (e < NB) baseq[e] = 0.0f;
  if (blockIdx.x == 0) {
    int z = threadIdx.x;
    float pz = sigclip(z_bias[z]);
    float lp = __logf(pz), l1 = __logf(1.0f - pz);
    d_lpz[z] = lp - l1;
    float s = blockReduceSum256(l1, red);
    if (z == 0) *basepz = s;
  }
}

// ---------------- KW: W[b][k] = sum_x (1-2*xin[b,x]) * bf16val(Vkpad2[x,k]) ----------
__global__ __launch_bounds__(256) void kW_signdot(const float* __restrict__ xin,
                                                  const ushort* __restrict__ Vkpad2,
                                                  float* __restrict__ W) {
  __shared__ float wred[4][NK];
  int b = blockIdx.x;
  int tid = threadIdx.x;
  float acc[NK];
#pragma unroll
  for (int j = 0; j < NK; ++j) acc[j] = 0.0f;
#pragma unroll
  for (int i = 0; i < 8; ++i) {
    int x = i * 256 + tid;
    float s = 1.0f - 2.0f * xin[(size_t)b * NX + x];
    const uint4* vp = (const uint4*)(Vkpad2 + (size_t)x * 32);
    uint4 q0 = vp[0], q1 = vp[1], q2 = vp[2], q3 = vp[3];
    uint32_t w[16] = {q0.x, q0.y, q0.z, q0.w, q1.x, q1.y, q1.z, q1.w,
                      q2.x, q2.y, q2.z, q2.w, q3.x, q3.y, q3.z, q3.w};
#pragma unroll
    for (int j = 0; j < NK; ++j) {
      uint32_t wd = w[j >> 1];
      float v = __uint_as_float((j & 1) ? (wd & 0xFFFF0000u) : (wd << 16));
      acc[j] = fmaf(s, v, acc[j]);
    }
  }
#pragma unroll
  for (int j = 0; j < NK; ++j) {
#pragma unroll
    for (int o = 1; o < 64; o <<= 1) acc[j] += __shfl_xor(acc[j], o);
  }
  if ((tid & 63) == 0) {
#pragma unroll
    for (int j = 0; j < NK; ++j) wred[tid >> 6][j] = acc[j];
  }
  __syncthreads();
  if (tid < NK) W[b * 32 + tid] = wred[0][tid] + wred[1][tid] + wred[2][tid] + wred[3][tid];
}

// ---------------- K1A: q-GEMM via MFMA hi/lo split-K (exact to ~fp32) ----------
// logit[b][z] = xin@U^T + z_bias; A=xinbf (exact), B=Uhi+Ulo. Block = 16b x 16z
// tile; 4 waves = 4 K-chunks of 512, frags direct from global (no barrier in
// K-loop), LDS cross-wave reduce, fused sigmoid/log epilogue + baseq atomics.
__global__ __launch_bounds__(256) void k1a_mfma(const ushort* __restrict__ xinbf,
                                                const ushort* __restrict__ Uhi,
                                                const ushort* __restrict__ Ulo,
                                                const float* __restrict__ z_bias,
                                                float* __restrict__ outq,
                                                float* __restrict__ d_lq,
                                                float* __restrict__ baseq) {
  __shared__ float red[4][16][17];
  int tid = threadIdx.x;
  int wave = tid >> 6, lane = tid & 63, grp = lane >> 4, col = lane & 15;
  int b0 = (blockIdx.x >> 4) * 16;
  int z0 = (blockIdx.x & 15) * 16;
  f32x4 acc = {0.f, 0.f, 0.f, 0.f};
  const ushort* arow = xinbf + (size_t)(b0 + col) * NX + wave * 512 + grp * 8;
  const ushort* bhr = Uhi + (size_t)(z0 + col) * NX + wave * 512 + grp * 8;
  const ushort* blr = Ulo + (size_t)(z0 + col) * NX + wave * 512 + grp * 8;
#pragma unroll 4
  for (int s = 0; s < 16; ++s) {
    bf16x8 a = *(const bf16x8*)(arow + s * 32);
    bf16x8 bh = *(const bf16x8*)(bhr + s * 32);
    bf16x8 bl = *(const bf16x8*)(blr + s * 32);
    acc = __builtin_amdgcn_mfma_f32_16x16x32_bf16(a, bh, acc, 0, 0, 0);
    acc = __builtin_amdgcn_mfma_f32_16x16x32_bf16(a, bl, acc, 0, 0, 0);
  }
#pragma unroll
  for (int r = 0; r < 4; ++r) red[wave][grp * 4 + r][col] = acc[r];
  __syncthreads();
  int bi = tid >> 4, zi = tid & 15;
  float aa = red[0][bi][zi] + red[1][bi][zi] + red[2][bi][zi] + red[3][bi][zi] + z_bias[z0 + zi];
  int b = b0 + bi, z = z0 + zi;
  float q = sigclip(aa);
  outq[b * NZ + z] = q;
  float lq = __logf(q), l1 = __logf(1.0f - q);
  d_lq[b * NZ + z] = lq - l1;
  float s1 = l1;
#pragma unroll
  for (int o = 1; o < 16; o <<= 1) s1 += __shfl_xor(s1, o);
  if (zi == 0) atomicAdd(&baseq[b], s1);
}

// ---------------- K2: samples_z (f32 + bf16) + packed bits + tails ----------------
__global__ __launch_bounds__(256) void k2_samples(const float* __restrict__ q,
                                                  const float* __restrict__ d_lq,
                                                  const float* __restrict__ d_lpz,
                                                  float* __restrict__ samp_out,
                                                  ushort* __restrict__ samp16,
                                                  ull* __restrict__ Spack,
                                                  float* __restrict__ qtail,
                                                  float* __restrict__ ptail,
                                                  uint32_t kz0, uint32_t kz1) {
  __shared__ float red[4];
  int sb = blockIdx.x;
  int z = threadIdx.x;
  int b = sb & (NB - 1);
  uint32_t i = (uint32_t)sb * NZ + z;
  const uint32_t h = (uint32_t)SBTOT * NZ / 2;
  float u = tf_uniform(kz0, kz1, i, h);
  float qv = q[b * NZ + z];
  int smp = (u < qv) ? 1 : 0;
  samp_out[i] = (float)smp;
  samp16[i] = smp ? (ushort)0x3F80 : (ushort)0;
  ull m = __ballot(smp);
  if ((z & 63) == 0) Spack[sb * 4 + (z >> 6)] = m;
  float dq = (z >= NK && smp) ? d_lq[b * NZ + z] : 0.0f;
  float dp = (z >= NK && smp) ? d_lpz[z] : 0.0f;
  float sq = blockReduceSum256(dq, red);
  float sp = blockReduceSum256(dp, red);
  if (z == 0) { qtail[sb] = sq; ptail[sb] = sp; }
}

// ---------------- K3M: bf16 MFMA GEMM (operand-swapped): C[x][sb] = V·samp^T ------
__global__ __launch_bounds__(256) void k3m_gemm(const ushort* __restrict__ samp16,
                                                const ushort* __restrict__ Vbf,
                                                const float* __restrict__ x_bias,
                                                ushort* __restrict__ base2,
                                                float* __restrict__ ps_out,
                                                float* __restrict__ xo_out,
                                                uint32_t kx0, uint32_t kx1) {
  __shared__ __align__(16) ushort As[128 * 32];  // V rows (x)     8 KB
  __shared__ __align__(16) ushort Bs[64 * 32];   // samp rows (sb) 4 KB
  int tid = threadIdx.x;
  int wave = tid >> 6, lane = tid & 63, grp = lane >> 4, col = lane & 15;
  int x0 = blockIdx.x * 128, sb0 = blockIdx.y * 64;
  f32x4 acc[2][4];
#pragma unroll
  for (int mi = 0; mi < 2; ++mi)
#pragma unroll
    for (int ni = 0; ni < 4; ++ni) acc[mi][ni] = (f32x4){0.f, 0.f, 0.f, 0.f};

  for (int k0 = 0; k0 < NZ; k0 += 32) {
    {
      int rowb = tid >> 2, kcb = (tid & 3) << 3;
      *(uint4*)&Bs[rowb * 32 + kcb] = *(const uint4*)&samp16[(size_t)(sb0 + rowb) * NZ + k0 + kcb];
#pragma unroll
      for (int c = tid; c < 512; c += 256) {
        int rowa = c >> 2, kca = (c & 3) << 3;
        *(uint4*)&As[rowa * 32 + kca] = *(const uint4*)&Vbf[(size_t)(x0 + rowa) * NZ + k0 + kca];
      }
    }
    __syncthreads();
    bf16x8 af[2], bfv[4];
#pragma unroll
    for (int mi = 0; mi < 2; ++mi)
      af[mi] = *(const bf16x8*)&As[(wave * 32 + mi * 16 + col) * 32 + grp * 8];
#pragma unroll
    for (int ni = 0; ni < 4; ++ni)
      bfv[ni] = *(const bf16x8*)&Bs[(ni * 16 + col) * 32 + grp * 8];
#pragma unroll
    for (int mi = 0; mi < 2; ++mi)
#pragma unroll
      for (int ni = 0; ni < 4; ++ni)
        acc[mi][ni] = __builtin_amdgcn_mfma_f32_16x16x32_bf16(af[mi], bfv[ni], acc[mi][ni], 0, 0, 0);
    __syncthreads();
  }
  const uint32_t h = (uint32_t)SBTOT * NX / 2;
#pragma unroll
  for (int mi = 0; mi < 2; ++mi) {
    int xb = x0 + wave * 32 + mi * 16 + grp * 4;  // 4 consecutive x per lane
    float4 xb4 = *(const float4*)(x_bias + xb);
#pragma unroll
    for (int ni = 0; ni < 4; ++ni) {
      int sb = sb0 + ni * 16 + col;
      size_t off = (size_t)sb * NX + xb;
      float a0 = acc[mi][ni][0] + xb4.x;
      float a1 = acc[mi][ni][1] + xb4.y;
      float a2 = acc[mi][ni][2] + xb4.z;
      float a3 = acc[mi][ni][3] + xb4.w;
      uint2 bp;
      bp.x = (uint32_t)f2bf(a0 * LOG2E) | ((uint32_t)f2bf(a1 * LOG2E) << 16);
      bp.y = (uint32_t)f2bf(a2 * LOG2E) | ((uint32_t)f2bf(a3 * LOG2E) << 16);
      *(uint2*)(base2 + off) = bp;
      float4 pv = make_float4(sigclip(a0), sigclip(a1), sigclip(a2), sigclip(a3));
      *(float4*)(ps_out + off) = pv;
      uint32_t fi = (uint32_t)sb * NX + xb;
      float4 xv;
      xv.x = (tf_uniform(kx0, kx1, fi + 0, h) < pv.x) ? 1.0f : 0.0f;
      xv.y = (tf_uniform(kx0, kx1, fi + 1, h) < pv.y) ? 1.0f : 0.0f;
      xv.z = (tf_uniform(kx0, kx1, fi + 2, h) < pv.z) ? 1.0f : 0.0f;
      xv.w = (tf_uniform(kx0, kx1, fi + 3, h) < pv.w) ? 1.0f : 0.0f;
      *(float4*)(xo_out + off) = xv;
    }
  }
}

// ---------------- K4: GF(2) row reduce (parallel bit-gen + wave0 elimination) ----------------
__global__ __launch_bounds__(256) void k4_rowreduce(ull* __restrict__ Ct,
                                                    uint32_t* __restrict__ bpmask,
                                                    uint32_t kA0, uint32_t kA1,
                                                    uint32_t kb0, uint32_t kb1) {
  __shared__ uint32_t Aw[NK][8];
  __shared__ uint32_t bbsh[NK];
  int t = blockIdx.x;
  int tid = threadIdx.x;
  if (tid < NK * 8) {
    int r = tid >> 3, c = tid & 7;
    const uint32_t hA = (uint32_t)NT * NK * NZ / 2;
    uint32_t base_i = (uint32_t)(t * NK + r) * NZ + c * 32;
    uint32_t w = 0;
    for (int zz = 0; zz < 32; ++zz) {
      uint32_t rr = tf_select(kA0, kA1, base_i + zz, hA);
      w |= ((rr >> 31) ^ 1u) << zz;  // bit=1 iff u<0.5 (top bit 0)
    }
    Aw[r][c] = w;
  }
  if (tid < NK) {
    const uint32_t hb = (uint32_t)NT * NK / 2;
    uint32_t rb = tf_select(kb0, kb1, (uint32_t)(t * NK + tid), hb);
    bbsh[tid] = (rb >> 31) ^ 1u;
  }
  __syncthreads();
  if (tid >= 64) return;  // wave 0 does the elimination
  int lane = tid;
  ull w0 = 0, w1 = 0, w2 = 0, w3 = 0;
  uint32_t bbit = 0;
  if (lane < NK) {
    w0 = (ull)Aw[lane][0] | ((ull)Aw[lane][1] << 32);
    w1 = (ull)Aw[lane][2] | ((ull)Aw[lane][3] << 32);
    w2 = (ull)Aw[lane][4] | ((ull)Aw[lane][5] << 32);
    w3 = (ull)Aw[lane][6] | ((ull)Aw[lane][7] << 32);
    bbit = bbsh[lane];
  }
  for (int i = 0; i < NK; ++i) {
    int mybit = (int)((w0 >> i) & 1ull);
    ull mask = __ballot(lane < NK && mybit);
    ull cand = mask & (~0ull << i);
    int p = cand ? __builtin_ctzll(cand) : (NK - 1);
    int srcl = (lane == i) ? p : ((lane == p) ? i : lane);
    w0 = __shfl(w0, srcl); w1 = __shfl(w1, srcl); w2 = __shfl(w2, srcl); w3 = __shfl(w3, srcl);
    bbit = __shfl(bbit, srcl);
    ull p0 = __shfl(w0, i), p1 = __shfl(w1, i), p2 = __shfl(w2, i), p3 = __shfl(w3, i);
    uint32_t pvb = __shfl(bbit, i);
    int nb2 = (int)((w0 >> i) & 1ull);
    if (lane < NK && lane != i && nb2) {
      w0 ^= p0; w1 ^= p1; w2 ^= p2; w3 ^= p3; bbit ^= pvb;
    }
  }
  if (lane < NK) {
    w0 &= ~((1ull << NK) - 1ull);  // only columns z>=k feed proj
    ull* dstp = Ct + (size_t)(t * NK + lane) * 4;
    dstp[0] = w0; dstp[1] = w1; dstp[2] = w2; dstp[3] = w3;
  }
  ull bm = __ballot(lane < NK && bbit);
  if (lane == 0) bpmask[t] = (uint32_t)bm & 0x1FFFFFFu;
}

// ---------------- K5: proj bits + Syd = sum_j d_j*W[b,j]; layout [sb*32+t] -------
__global__ __launch_bounds__(256) void k5_proj(const ull* __restrict__ Spack,
                                               const ull* __restrict__ Ct,
                                               const uint32_t* __restrict__ bpmask,
                                               const float* __restrict__ W,
                                               uint32_t* __restrict__ projb,
                                               float* __restrict__ Syd) {
  int e = blockIdx.x * 256 + threadIdx.x;  // < SBTOT*32
  int sb = e >> 5, t = e & 31;
  ull s0 = Spack[sb * 4 + 0], s1 = Spack[sb * 4 + 1];
  ull s2 = Spack[sb * 4 + 2], s3 = Spack[sb * 4 + 3];
  uint32_t s25 = (uint32_t)(s0 & 0x1FFFFFFull);
  const float* Wb = W + (size_t)(sb & (NB - 1)) * 32;
  uint32_t out;
  float syd = 0.0f;
  if (t < NT) {
    uint32_t bp = bpmask[t];
    uint32_t pb = 0;
#pragma unroll
    for (int j = 0; j < NK; ++j) {
      const ull* C = Ct + (size_t)(t * NK + j) * 4;
      int par = __popcll(s0 & C[0]) + __popcll(s1 & C[1]) + __popcll(s2 & C[2]) + __popcll(s3 & C[3]);
      uint32_t bit = ((uint32_t)(par ^ (int)(bp >> j))) & 1u;
      pb |= bit << j;
      int d = (int)bit - (int)((s25 >> j) & 1u);
      syd = fmaf((float)d, Wb[j], syd);
    }
    out = pb;
  } else {
    out = s25;  // d = pb - s25 = 0
  }
  projb[e] = out;
  Syd[e] = syd;
}

// ---------------- K6: logp_x via MFMA delta-GEMM + fused softplus (log2-space) ----------
__global__ __launch_bounds__(256) void k6_mfma(const ushort* __restrict__ base2,
                                               const ushort* __restrict__ Vkpad2,
                                               const float* __restrict__ xin,
                                               const uint32_t* __restrict__ projb,
                                               const ull* __restrict__ Spack,
                                               const float* __restrict__ Syd,
                                               float* __restrict__ logpx) {
  __shared__ float bvsm[NX];  // b2 per x — 8 KB
  __shared__ float lsum[4][32];
  __shared__ float red[4];
  int sb = blockIdx.x;
  int b = sb & (NB - 1);
  int tid = threadIdx.x;
  int wave = tid >> 6, lane = tid & 63;
  int grp = lane >> 4, col = lane & 15;
  // stage base2 row (bf16 -> f32) + analytic sum_x s*b2
  const uint4* b16p = (const uint4*)(base2 + (size_t)sb * NX);
  const float4* x4p = (const float4*)(xin + (size_t)b * NX);
  float sbacc = 0.0f;
  {
    uint4 bu = b16p[tid];
    float4 xv0 = x4p[tid * 2], xv1 = x4p[tid * 2 + 1];
    uint32_t wds[4] = {bu.x, bu.y, bu.z, bu.w};
    float bv[8];
#pragma unroll
    for (int j = 0; j < 8; ++j) {
      uint32_t wd = wds[j >> 1];
      bv[j] = __uint_as_float((j & 1) ? (wd & 0xFFFF0000u) : (wd << 16));
    }
    float sg[8] = {1.0f - 2.0f * xv0.x, 1.0f - 2.0f * xv0.y, 1.0f - 2.0f * xv0.z,
                   1.0f - 2.0f * xv0.w, 1.0f - 2.0f * xv1.x, 1.0f - 2.0f * xv1.y,
                   1.0f - 2.0f * xv1.z, 1.0f - 2.0f * xv1.w};
#pragma unroll
    for (int j = 0; j < 8; ++j) {
      bvsm[tid * 8 + j] = bv[j];
      sbacc = fmaf(sg[j], bv[j], sbacc);
    }
  }
  float Sb = blockReduceSum256(sbacc, red);  // includes syncthreads (guards bvsm)
  // A-frags: lane holds m=col (t within tile), k = grp*8+j
  uint32_t s25 = (uint32_t)(Spack[sb * 4] & 0x1FFFFFFull);
  uint32_t pb0 = projb[sb * 32 + col];
  uint32_t pb1 = projb[sb * 32 + 16 + col];
  bf16x8 a0, a1;
  union { ushort u; __bf16 hh; } cvt;
#pragma unroll
  for (int j = 0; j < 8; ++j) {
    int k = grp * 8 + j;
    int sbit = (int)((s25 >> k) & 1u);
    int d0 = (int)((pb0 >> k) & 1u) - sbit;
    int d1 = (int)((pb1 >> k) & 1u) - sbit;
    cvt.u = (ushort)(d0 == 0 ? 0 : (d0 > 0 ? 0x3F80 : 0xBF80)); a0[j] = cvt.hh;
    cvt.u = (ushort)(d1 == 0 ? 0 : (d1 > 0 ? 0x3F80 : 0xBF80)); a1[j] = cvt.hh;
  }
  float acca[8], pp[8];
#pragma unroll
  for (int r = 0; r < 8; ++r) { acca[r] = 0.0f; pp[r] = 1.0f; }
  const ushort* vkbase = Vkpad2 + (size_t)(wave * 512 + col) * 32 + grp * 8;
#pragma unroll 4
  for (int i = 0; i < 32; ++i) {
    int x = (wave * 32 + i) * 16 + col;
    bf16x8 bfr = *(const bf16x8*)(vkbase + (size_t)i * 16 * 32);
    f32x4 c0 = {0.f, 0.f, 0.f, 0.f}, c1 = {0.f, 0.f, 0.f, 0.f};
    c0 = __builtin_amdgcn_mfma_f32_16x16x32_bf16(a0, bfr, c0, 0, 0, 0);
    c1 = __builtin_amdgcn_mfma_f32_16x16x32_bf16(a1, bfr, c1, 0, 0, 0);
    float bs = bvsm[x];
#pragma unroll
    for (int r = 0; r < 4; ++r) {
      float y0 = bs + c0[r];
      acca[r] += fabsf(y0);
      pp[r] = fmaf(pp[r], __builtin_amdgcn_exp2f(-fabsf(y0)), pp[r]);
      float y1 = bs + c1[r];
      acca[4 + r] += fabsf(y1);
      pp[4 + r] = fmaf(pp[4 + r], __builtin_amdgcn_exp2f(-fabsf(y1)), pp[4 + r]);
    }
  }
#pragma unroll
  for (int r = 0; r < 8; ++r) {
    float m = 0.5f * acca[r] + __log2f(pp[r]);
#pragma unroll
    for (int off = 1; off < 16; off <<= 1) m += __shfl_xor(m, off);
    if (col == 0) {
      int t = (r < 4) ? (grp * 4 + r) : (16 + grp * 4 + (r - 4));
      lsum[wave][t] = m;
    }
  }
  __syncthreads();
  if (tid < NT) {
    float tot = lsum[0][tid] + lsum[1][tid] + lsum[2][tid] + lsum[3][tid];
    tot += 0.5f * (Sb + Syd[sb * 32 + tid]);
    logpx[(size_t)tid * SBTOT + sb] = -LN2 * tot;
  }
}

// ---------------- K7: per-t weighted reduction over (s,b) ----------------
__global__ __launch_bounds__(512) void k7_reduce(const float* __restrict__ logpx,
                                                 const uint32_t* __restrict__ projb,
                                                 const float* __restrict__ qtail,
                                                 const float* __restrict__ ptail,
                                                 const float* __restrict__ baseq,
                                                 const float* __restrict__ d_lq,
                                                 const float* __restrict__ d_lpz,
                                                 const float* __restrict__ basepz,
                                                 double* __restrict__ pelbo) {
  __shared__ double red8[8];
  int t = blockIdx.x;
  int b = threadIdx.x;
  float dlq[NK];
#pragma unroll
  for (int j = 0; j < NK; ++j) dlq[j] = d_lq[b * NZ + j];
  float bq = baseq[b];
  float bpz = *basepz;
  float lq[NS], lp[NS];
#pragma unroll
  for (int s = 0; s < NS; ++s) {
    int sb = s * NB + b;
    uint32_t m = projb[sb * 32 + t];
    float sq = 0.0f, spv = 0.0f;
#pragma unroll
    for (int j = 0; j < NK; ++j) {
      float on = (float)((m >> j) & 1u);
      sq += on * dlq[j];
      spv += on * d_lpz[j];
    }
    lq[s] = bq + qtail[sb] + sq;
    lp[s] = logpx[t * SBTOT + sb] + bpz + ptail[sb] + spv;
  }
  float mx = lq[0];
#pragma unroll
  for (int s = 1; s < NS; ++s) mx = fmaxf(mx, lq[s]);
  float den = 0.0f, num = 0.0f;
#pragma unroll
  for (int s = 0; s < NS; ++s) {
    float w = __expf(lq[s] - mx);
    den += w;
    num += w * (lq[s] - lp[s]);
  }
  double v = (double)(num / den);
#pragma unroll
  for (int o = 32; o > 0; o >>= 1) v += __shfl_down(v, o);
  __syncthreads();
  if ((b & 63) == 0) red8[b >> 6] = v;
  __syncthreads();
  if (b == 0) {
    double s = 0.0;
    for (int i = 0; i < 8; ++i) s += red8[i];
    pelbo[t] = s;
  }
}

// ---------------- K8: final loss ----------------
__global__ __launch_bounds__(64) void k8_loss(const double* __restrict__ pelbo,
                                              float* __restrict__ out_loss) {
  int t = threadIdx.x;
  double v = (t < NT) ? pelbo[t] : 0.0;
#pragma unroll
  for (int o = 32; o > 0; o >>= 1) v += __shfl_down(v, o);
  if (t == 0) *out_loss = (float)(v / (double)NT);
}

extern "C" void kernel_launch(void* const* d_in, const int* in_sizes, int n_in,
                              void* d_out, int out_size, void* d_ws, size_t ws_size,
                              hipStream_t stream) {
  const float* xin = (const float*)d_in[0];
  const float* U = (const float*)d_in[1];
  const float* V = (const float*)d_in[2];
  const float* x_bias = (const float*)d_in[3];
  const float* z_bias = (const float*)d_in[4];
  float* out = (float*)d_out;

  char* p = (char*)d_ws;
  ushort* base2 = (ushort*)p;             p += (size_t)SBTOT * NX * 2;
  float* d_lq = (float*)p;                p += (size_t)NB * NZ * 4;
  float* baseq = (float*)p;               p += (size_t)NB * 4;
  float* d_lpz = (float*)p;               p += (size_t)NZ * 4;
  float* basepz = (float*)p;              p += 16;
  ull* Spack = (ull*)p;                   p += (size_t)SBTOT * 4 * 8;
  float* qtail = (float*)p;               p += (size_t)SBTOT * 4;
  float* ptail = (float*)p;               p += (size_t)SBTOT * 4;
  ull* Ct = (ull*)p;                      p += (size_t)NT * NK * 4 * 8;
  uint32_t* bpm = (uint32_t*)p;           p += 128;
  uint32_t* projb = (uint32_t*)p;         p += (size_t)SBTOT * 32 * 4;
  float* Syd = (float*)p;                 p += (size_t)SBTOT * 32 * 4;
  float* logpx = (float*)p;               p += (size_t)NT * SBTOT * 4;
  double* pelbo = (double*)p;             p += (size_t)NT * 8;
  ushort* Vkpad2 = (ushort*)p;            p += (size_t)NX * 32 * 2;
  ushort* Vbf = (ushort*)p;               p += (size_t)NX * NZ * 2;
  ushort* samp16 = (ushort*)p;            p += (size_t)SBTOT * NZ * 2;
  float* W = (float*)p;                   p += (size_t)NB * 32 * 4;
  ushort* Uhi = (ushort*)p;               p += (size_t)NZ * NX * 2;
  ushort* Ulo = (ushort*)p;               p += (size_t)NZ * NX * 2;
  ushort* xinbf = (ushort*)p;             p += (size_t)NB * NX * 2;
  (void)ws_size; (void)in_sizes; (void)n_in; (void)out_size;

  // JAX: key(42) -> split 4 -> kz,kx,kA,kb
  uint32_t o0[4], o1[4];
  for (int j = 0; j < 4; ++j) tf2x32(0u, 42u, (uint32_t)j, (uint32_t)(4 + j), o0[j], o1[j]);
  uint32_t kz0 = o0[0], kz1 = o0[1];
  uint32_t kx0 = o0[2], kx1 = o0[3];
  uint32_t kA0 = o1[0], kA1 = o1[1];
  uint32_t kb0 = o1[2], kb1 = o1[3];

  kP0_prep<<<NX * NZ / 256, 256, 0, stream>>>(V, U, xin, z_bias, Vbf, Vkpad2,
                                              Uhi, Ulo, xinbf, baseq, d_lpz, basepz);
  k4_rowreduce<<<NT, 256, 0, stream>>>(Ct, bpm, kA0, kA1, kb0, kb1);
  k1a_mfma<<<512, 256, 0, stream>>>(xinbf, Uhi, Ulo, z_bias, out + OFF_Q, d_lq, baseq);
  kW_signdot<<<NB, 256, 0, stream>>>(xin, Vkpad2, W);
  k2_samples<<<SBTOT, 256, 0, stream>>>(out + OFF_Q, d_lq, d_lpz, out + OFF_SAMP,
                                        samp16, Spack, qtail, ptail, kz0, kz1);
  dim3 g3(NX / 128, SBTOT / 64);
  k3m_gemm<<<g3, 256, 0, stream>>>(samp16, Vbf, x_bias, base2,
                                   out + OFF_PS, out + OFF_XO, kx0, kx1);
  k5_proj<<<SBTOT * 32 / 256, 256, 0, stream>>>(Spack, Ct, bpm, W, projb, Syd);
  k6_mfma<<<SBTOT, 256, 0, stream>>>(base2, Vkpad2, xin, projb, Spack, Syd, logpx);
  k7_reduce<<<NT, 512, 0, stream>>>(logpx, projb, qtail, ptail, baseq, d_lq,
                                    d_lpz, basepz, pelbo);
  k8_loss<<<1, 64, 0, stream>>>(pelbo, out + OFF_LOSS);
}